// Round 8
// baseline (675.344 us; speedup 1.0000x reference)
//
#include <hip/hip_runtime.h>
#include <hip/hip_bf16.h>

namespace {

constexpr int B = 2;
constexpr int N = 40000;
constexpr int E = 400000;
constexpr int R = 64;
constexpr int D = 64;
constexpr int L = 6;
constexpr float EPS = 1e-5f;
constexpr int NB = (N + 255) / 256;   // 157 node-grid blocks
constexpr int EB = (E + 255) / 256;   // 1563 edge-grid blocks

// Compiler-only memory barrier: blocks TBAA-based reordering of the
// vector-cast LDS reads above the typed LDS writes.
__device__ __forceinline__ void compiler_fence() { asm volatile("" ::: "memory"); }

__device__ __forceinline__ unsigned int pack_bf2(float lo, float hi) {
  unsigned int ulo = (__float_as_uint(lo) + 0x8000u) >> 16;
  unsigned int uhi = (__float_as_uint(hi) + 0x8000u) & 0xffff0000u;
  return (ulo & 0xffffu) | uhi;
}
__device__ __forceinline__ float bflo(unsigned int u) { return __uint_as_float(u << 16); }
__device__ __forceinline__ float bfhi(unsigned int u) { return __uint_as_float(u & 0xffff0000u); }

// Batch-interleaved layout: float2 / packed-uint element = (batch0, batch1).

// ---- query gather + boundary scatter (x_f, xb must be pre-zeroed) ----
__global__ void k_init(const float* __restrict__ rel_reps,
                       const int* __restrict__ h_index, const int* __restrict__ r_index,
                       float* __restrict__ x_f, unsigned int* __restrict__ xb,
                       float* __restrict__ query_f) {
  int d = threadIdx.x;               // 64 threads
  int h0 = h_index[0], h1 = h_index[1];
  float q0 = rel_reps[r_index[0] * D + d];
  float q1 = rel_reps[(R + r_index[1]) * D + d];
  query_f[d * 2] = q0; query_f[d * 2 + 1] = q1;
  x_f[(size_t)h0 * 2 * D + d * 2]     = q0;
  x_f[(size_t)h1 * 2 * D + d * 2 + 1] = q1;
  if (h0 == h1) {
    xb[(size_t)h0 * D + d] = pack_bf2(q0, q1);
  } else {
    xb[(size_t)h0 * D + d] = pack_bf2(q0, 0.f);
    xb[(size_t)h1 * D + d] = pack_bf2(0.f, q1);
  }
}

// ---- relation projection MLP for all layers: rel2[l][r*64+d] = (b0, b1) ----
__global__ __launch_bounds__(64) void k_rel(
    const float* __restrict__ rel_reps,
    const float* __restrict__ pw1, const float* __restrict__ pb1,
    const float* __restrict__ pw2, const float* __restrict__ pb2,
    float* __restrict__ rel_f) {
  __shared__ float row[D];
  __shared__ float row2[D];
  int idx = blockIdx.x;             // [0, L*B*R)
  int l = idx / (B * R);
  int br = idx - l * (B * R);       // b*R + r
  int b = br / R, r = br - b * R;
  int d = threadIdx.x;
  row[d] = rel_reps[(size_t)br * D + d];
  __syncthreads();
  const float* w1 = pw1 + (size_t)l * D * D;
  float acc = pb1[l * D + d];
  for (int k = 0; k < D; ++k) acc = fmaf(row[k], w1[k * D + d], acc);
  row2[d] = fmaxf(acc, 0.f);
  __syncthreads();
  const float* w2 = pw2 + (size_t)l * D * D;
  float acc2 = pb2[l * D + d];
  for (int k = 0; k < D; ++k) acc2 = fmaf(row2[k], w2[k * D + d], acc2);
  rel_f[(((size_t)l * R + r) * D + d) * 2 + b] = acc2;
}

// pack rel fp32-float2 -> bf16x2 dword (L*R*D entries)
__global__ __launch_bounds__(256) void k_pack_rel(const float2* __restrict__ rel2,
                                                  unsigned int* __restrict__ rel_pk) {
  int i = blockIdx.x * 256 + threadIdx.x;
  if (i < L * R * D) {
    float2 v = rel2[i];
    rel_pk[i] = pack_bf2(v.x, v.y);
  }
}

// ---- CSR build ----
__global__ __launch_bounds__(256) void k_hist(const int* __restrict__ dst,
                                              int* __restrict__ cnt) {
  int e = blockIdx.x * 256 + threadIdx.x;
  if (e < E) atomicAdd(&cnt[dst[e]], 1);
}

__global__ __launch_bounds__(256) void k_scan1(const int* __restrict__ cnt,
                                               int* __restrict__ row_ptr,
                                               int* __restrict__ bsum) {
  __shared__ int s[256];
  int t = threadIdx.x;
  int i = blockIdx.x * 256 + t;
  int v = (i < N) ? cnt[i] : 0;
  s[t] = v;
  __syncthreads();
  #pragma unroll
  for (int off = 1; off < 256; off <<= 1) {   // Hillis-Steele inclusive
    int u = (t >= off) ? s[t - off] : 0;
    __syncthreads();
    s[t] += u;
    __syncthreads();
  }
  if (i < N) row_ptr[i] = s[t] - v;           // exclusive-in-block
  if (t == 255) bsum[blockIdx.x] = s[255];
}

__global__ __launch_bounds__(256) void k_scan2(int* __restrict__ bsum,
                                               int* __restrict__ row_ptr) {
  __shared__ int s[NB];
  int t = threadIdx.x;
  if (t < NB) s[t] = bsum[t];
  __syncthreads();
  if (t == 0) {
    int run = 0;
    for (int i = 0; i < NB; ++i) { int v = s[i]; s[i] = run; run += v; }
    row_ptr[N] = run;                         // = E
  }
  __syncthreads();
  if (t < NB) bsum[t] = s[t];
}

__global__ __launch_bounds__(256) void k_scan3(int* __restrict__ row_ptr,
                                               const int* __restrict__ bsum,
                                               int* __restrict__ cursor) {
  int i = blockIdx.x * 256 + threadIdx.x;
  if (i < N) {
    int v = row_ptr[i] + bsum[blockIdx.x];
    row_ptr[i] = v;
    cursor[i] = v;
  }
}

__global__ __launch_bounds__(256) void k_fill(const int* __restrict__ src,
                                              const int* __restrict__ dst,
                                              const int* __restrict__ etype,
                                              int* __restrict__ cursor,
                                              unsigned int* __restrict__ es) {
  int e = blockIdx.x * 256 + threadIdx.x;
  if (e < E) {
    int p = atomicAdd(&cursor[dst[e]], 1);
    es[p] = (unsigned int)src[e] | ((unsigned int)etype[e] << 16);  // src < 65536
  }
}

// ---- gather: one wave per node; bf16-packed x (one dword/edge/lane) +
// LDS-staged bf16 rel (16 KB). fp32 accumulation. 8 blocks/CU.
__global__ __launch_bounds__(256, 8) void k_gather(
    const unsigned int* __restrict__ xb, float2* __restrict__ agg,
    const unsigned int* __restrict__ rel_pk,     // [R*D] this layer, packed
    const int* __restrict__ row_ptr, const unsigned int* __restrict__ es,
    const float2* __restrict__ q2, const int* __restrict__ h_index, int first) {
  __shared__ unsigned int rel_lds[R * D];        // 16 KB
  int tid = threadIdx.x;
  for (int i = tid; i < R * D; i += 256) rel_lds[i] = rel_pk[i];
  __syncthreads();
  int lane = tid & 63;
  int n = (blockIdx.x * 256 + tid) >> 6;         // node; grid covers N exactly
  int h0 = h_index[0], h1 = h_index[1];
  int rs = row_ptr[n], re = row_ptr[n + 1];
  int m = min(re - rs, 64);
  unsigned int pkl = 0;
  if (lane < m) pkl = es[rs + lane];             // whole edge list, one load
  float a0 = 0.f, a1 = 0.f;
  if (first) {
    // layer 0: x nonzero only at h0 (.x) and h1 (.y)
    for (int j = 0; j < m; ++j) {
      unsigned int pk = __shfl(pkl, j);
      int s  = (int)(pk & 0xffffu);
      int et = (int)(pk >> 16);
      if (s == h0) a0 = fmaf(bflo(xb[(size_t)s * D + lane]), bflo(rel_lds[et * D + lane]), a0);
      if (s == h1) a1 = fmaf(bfhi(xb[(size_t)s * D + lane]), bfhi(rel_lds[et * D + lane]), a1);
    }
    for (int jj = rs + 64; jj < re; ++jj) {      // deg>64 overflow (rare)
      unsigned int pk = es[jj];
      int s  = (int)(pk & 0xffffu);
      int et = (int)(pk >> 16);
      if (s == h0) a0 = fmaf(bflo(xb[(size_t)s * D + lane]), bflo(rel_lds[et * D + lane]), a0);
      if (s == h1) a1 = fmaf(bfhi(xb[(size_t)s * D + lane]), bfhi(rel_lds[et * D + lane]), a1);
    }
  } else {
    int j = 0;
    for (; j + 4 <= m; j += 4) {                 // 4 independent global loads in flight
      unsigned int p0 = __shfl(pkl, j),     p1 = __shfl(pkl, j + 1);
      unsigned int p2 = __shfl(pkl, j + 2), p3 = __shfl(pkl, j + 3);
      unsigned int xa = xb[(size_t)(p0 & 0xffffu) * D + lane];
      unsigned int xb_ = xb[(size_t)(p1 & 0xffffu) * D + lane];
      unsigned int xc = xb[(size_t)(p2 & 0xffffu) * D + lane];
      unsigned int xd = xb[(size_t)(p3 & 0xffffu) * D + lane];
      unsigned int ra = rel_lds[(p0 >> 16) * D + lane];
      unsigned int rb = rel_lds[(p1 >> 16) * D + lane];
      unsigned int rc = rel_lds[(p2 >> 16) * D + lane];
      unsigned int rd = rel_lds[(p3 >> 16) * D + lane];
      a0 = fmaf(bflo(xa), bflo(ra), a0); a1 = fmaf(bfhi(xa), bfhi(ra), a1);
      a0 = fmaf(bflo(xb_), bflo(rb), a0); a1 = fmaf(bfhi(xb_), bfhi(rb), a1);
      a0 = fmaf(bflo(xc), bflo(rc), a0); a1 = fmaf(bfhi(xc), bfhi(rc), a1);
      a0 = fmaf(bflo(xd), bflo(rd), a0); a1 = fmaf(bfhi(xd), bfhi(rd), a1);
    }
    for (; j < m; ++j) {
      unsigned int pk = __shfl(pkl, j);
      unsigned int xv = xb[(size_t)(pk & 0xffffu) * D + lane];
      unsigned int rv = rel_lds[(pk >> 16) * D + lane];
      a0 = fmaf(bflo(xv), bflo(rv), a0); a1 = fmaf(bfhi(xv), bfhi(rv), a1);
    }
    for (int jj = rs + 64; jj < re; ++jj) {      // deg>64 overflow (rare)
      unsigned int pk = es[jj];
      unsigned int xv = xb[(size_t)(pk & 0xffffu) * D + lane];
      unsigned int rv = rel_lds[(pk >> 16) * D + lane];
      a0 = fmaf(bflo(xv), bflo(rv), a0); a1 = fmaf(bfhi(xv), bfhi(rv), a1);
    }
  }
  if (n == h0) a0 += q2[lane].x;                 // + boundary (fp32)
  if (n == h1) a1 += q2[lane].y;
  agg[(size_t)n * D + lane] = make_float2(a0, a1);
}

// ---- linear + LN + relu + shortcut, in place on the agg buffer ----
// 512 threads = 8 waves; 8 nodes/wave as 2 groups of 4; also writes packed x copy.
__global__ __launch_bounds__(512) void k_linear(
    const float2* __restrict__ xo, float2* __restrict__ xn,   // xn holds agg on entry
    unsigned int* __restrict__ xnb,                            // packed copy of new x
    const float* __restrict__ lin_w, const float* __restrict__ lin_b,
    const float* __restrict__ ln_g, const float* __restrict__ ln_b,
    int layer) {
  __shared__ float2 wpk[D][D];         // wpk[k2][out] = (w[2k2][out], w[2k2+1][out]), 32 KB
  __shared__ float bias_s[D], g_s[D], b_s[D];
  __shared__ float2 rows[8][4][2 * D]; // per-wave, 4 nodes, concat row; 32 KB
  int tid = threadIdx.x;
  const float* lw = lin_w + (size_t)layer * 2 * D * D;
  for (int i = tid; i < D * D; i += 512) {
    int k2 = i >> 6, out = i & 63;
    wpk[k2][out] = make_float2(lw[(2 * k2) * D + out], lw[(2 * k2 + 1) * D + out]);
  }
  if (tid < D) {
    bias_s[tid] = lin_b[layer * D + tid];
    g_s[tid]    = ln_g[layer * D + tid];
    b_s[tid]    = ln_b[layer * D + tid];
  }
  __syncthreads();                     // weight staging
  int wid = tid >> 6, lane = tid & 63;
  int base = (blockIdx.x * 8 + wid) * 8;
  #pragma unroll 1
  for (int g = 0; g < 2; ++g) {
    int gbase = base + g * 4;
    #pragma unroll
    for (int ni = 0; ni < 4; ++ni) {
      int n = gbase + ni;
      rows[wid][ni][lane]     = xo[(size_t)n * D + lane];
      rows[wid][ni][D + lane] = xn[(size_t)n * D + lane];   // agg
    }
    compiler_fence();   // keep float4 reads below the float2 writes (TBAA)
    float o0[4], o1[4];
    #pragma unroll
    for (int ni = 0; ni < 4; ++ni) { o0[ni] = bias_s[lane]; o1[ni] = o0[ni]; }
    #pragma unroll 4
    for (int k2 = 0; k2 < D; ++k2) {
      float2 wk = wpk[k2][lane];
      #pragma unroll
      for (int ni = 0; ni < 4; ++ni) {
        float4 rr = ((const float4*)&rows[wid][ni][0])[k2];  // 16 B broadcast
        o0[ni] = fmaf(rr.x, wk.x, o0[ni]); o1[ni] = fmaf(rr.y, wk.x, o1[ni]);
        o0[ni] = fmaf(rr.z, wk.y, o0[ni]); o1[ni] = fmaf(rr.w, wk.y, o1[ni]);
      }
    }
    #pragma unroll
    for (int ni = 0; ni < 4; ++ni) {
      int n = gbase + ni;
      float s10 = o0[ni], s20 = o0[ni] * o0[ni];
      float s11 = o1[ni], s21 = o1[ni] * o1[ni];
      #pragma unroll
      for (int m = 32; m > 0; m >>= 1) {
        s10 += __shfl_xor(s10, m); s20 += __shfl_xor(s20, m);
        s11 += __shfl_xor(s11, m); s21 += __shfl_xor(s21, m);
      }
      float mu0 = s10 * (1.f / D), var0 = s20 * (1.f / D) - mu0 * mu0;
      float mu1 = s11 * (1.f / D), var1 = s21 * (1.f / D) - mu1 * mu1;
      float2 xv = rows[wid][ni][lane];
      float r0 = fmaxf((o0[ni] - mu0) * rsqrtf(var0 + EPS) * g_s[lane] + b_s[lane], 0.f) + xv.x;
      float r1 = fmaxf((o1[ni] - mu1) * rsqrtf(var1 + EPS) * g_s[lane] + b_s[lane], 0.f) + xv.y;
      xn[(size_t)n * D + lane] = make_float2(r0, r1);   // in place: row owned by this wave
      xnb[(size_t)n * D + lane] = pack_bf2(r0, r1);     // packed copy for next gather
    }
  }
}

// ---- final MLP: relu(concat(x, query) @ mlp_w + mlp_b) -> fp32 out ----
// 256 threads = 4 waves, 4 nodes/wave -> grid 2500; packed-bf16 x input.
__global__ __launch_bounds__(256) void k_mlp(
    const unsigned int* __restrict__ xb, const float2* __restrict__ q2,
    const float* __restrict__ mlp_w,            // [2D][2D] row-major fp32
    const float* __restrict__ mlp_b,
    float2* __restrict__ out) {
  __shared__ uint2 wpk[D][D];             // [k2][colpair], bf16-packed; 32 KB
  __shared__ unsigned int rowsx[4][4][D]; // packed x half; 4 KB
  __shared__ float2 q2s[D];               // query half fp32; 512 B
  int tid = threadIdx.x;
  for (int i = tid; i < D * D; i += 256) {
    int k2 = i >> 6, jp = i & 63;
    const float* w0 = mlp_w + (size_t)(2 * k2) * 2 * D;
    const float* w1 = mlp_w + (size_t)(2 * k2 + 1) * 2 * D;
    wpk[k2][jp] = make_uint2(pack_bf2(w0[2 * jp], w0[2 * jp + 1]),
                             pack_bf2(w1[2 * jp], w1[2 * jp + 1]));
  }
  if (tid < D) q2s[tid] = q2[tid];
  __syncthreads();
  int wid = tid >> 6, lane = tid & 63;
  float b0 = mlp_b[2 * lane], b1 = mlp_b[2 * lane + 1];
  int gbase = blockIdx.x * 16 + wid * 4;     // N = 40000 = 2500 blocks * 16
  #pragma unroll
  for (int ni = 0; ni < 4; ++ni)
    rowsx[wid][ni][lane] = xb[(size_t)(gbase + ni) * D + lane];
  compiler_fence();
  float a00[4], a01[4], a10[4], a11[4];
  #pragma unroll
  for (int ni = 0; ni < 4; ++ni) { a00[ni] = b0; a01[ni] = b1; a10[ni] = b0; a11[ni] = b1; }
  #pragma unroll 4
  for (int k2 = 0; k2 < D / 2; ++k2) {      // x half: rows k = 2k2, 2k2+1
    uint2 wv = wpk[k2][lane];
    float w00 = bflo(wv.x), w01 = bfhi(wv.x);
    float w10 = bflo(wv.y), w11 = bfhi(wv.y);
    #pragma unroll
    for (int ni = 0; ni < 4; ++ni) {
      uint2 xv = ((const uint2*)&rowsx[wid][ni][0])[k2];
      float xe0 = bflo(xv.x), xe1 = bfhi(xv.x);   // k=2k2:   b0, b1
      float xo0 = bflo(xv.y), xo1 = bfhi(xv.y);   // k=2k2+1: b0, b1
      a00[ni] = fmaf(xe0, w00, a00[ni]); a01[ni] = fmaf(xe0, w01, a01[ni]);
      a10[ni] = fmaf(xe1, w00, a10[ni]); a11[ni] = fmaf(xe1, w01, a11[ni]);
      a00[ni] = fmaf(xo0, w10, a00[ni]); a01[ni] = fmaf(xo0, w11, a01[ni]);
      a10[ni] = fmaf(xo1, w10, a10[ni]); a11[ni] = fmaf(xo1, w11, a11[ni]);
    }
  }
  #pragma unroll 4
  for (int k2 = D / 2; k2 < D; ++k2) {      // query half: rows k = 2k2 in [64,128)
    uint2 wv = wpk[k2][lane];
    float w00 = bflo(wv.x), w01 = bfhi(wv.x);
    float w10 = bflo(wv.y), w11 = bfhi(wv.y);
    float4 qq = ((const float4*)q2s)[k2 - D / 2];   // (q_even b0,b1, q_odd b0,b1)
    #pragma unroll
    for (int ni = 0; ni < 4; ++ni) {
      a00[ni] = fmaf(qq.x, w00, a00[ni]); a01[ni] = fmaf(qq.x, w01, a01[ni]);
      a10[ni] = fmaf(qq.y, w00, a10[ni]); a11[ni] = fmaf(qq.y, w01, a11[ni]);
      a00[ni] = fmaf(qq.z, w10, a00[ni]); a01[ni] = fmaf(qq.z, w11, a01[ni]);
      a10[ni] = fmaf(qq.w, w10, a10[ni]); a11[ni] = fmaf(qq.w, w11, a11[ni]);
    }
  }
  #pragma unroll
  for (int ni = 0; ni < 4; ++ni) {
    int n = gbase + ni;
    out[(size_t)n * D + lane] = make_float2(fmaxf(a00[ni], 0.f), fmaxf(a01[ni], 0.f));
    out[((size_t)N + n) * D + lane] = make_float2(fmaxf(a10[ni], 0.f), fmaxf(a11[ni], 0.f));
  }
}

}  // namespace

extern "C" void kernel_launch(void* const* d_in, const int* in_sizes, int n_in,
                              void* d_out, int out_size, void* d_ws, size_t ws_size,
                              hipStream_t stream) {
  const float* rel_reps = (const float*)d_in[0];
  const int* h_index    = (const int*)d_in[1];
  const int* r_index    = (const int*)d_in[2];
  const int* edge_index = (const int*)d_in[3];
  const int* edge_type  = (const int*)d_in[4];
  const float* proj_w1  = (const float*)d_in[5];
  const float* proj_b1  = (const float*)d_in[6];
  const float* proj_w2  = (const float*)d_in[7];
  const float* proj_b2  = (const float*)d_in[8];
  const float* lin_w    = (const float*)d_in[9];
  const float* lin_b    = (const float*)d_in[10];
  const float* ln_g     = (const float*)d_in[11];
  const float* ln_b     = (const float*)d_in[12];
  const float* mlp_w    = (const float*)d_in[13];
  const float* mlp_b    = (const float*)d_in[14];

  // workspace: x0 | x1 (fp32 float2) | rel_all | query | cnt | row_ptr | cursor |
  //            es | bsum | xb0 | xb1 (packed) | rel_pk
  float* x0      = (float*)d_ws;                       // N*D float2
  float* x1      = x0 + (size_t)2 * N * D;
  float* rel_all = x1 + (size_t)2 * N * D;             // L*R*D float2
  float* query   = rel_all + (size_t)2 * L * R * D;    // D float2
  int*   cnt     = (int*)(query + 2 * D);
  int*   row_ptr = cnt + N;
  int*   cursor  = row_ptr + (N + 1);
  unsigned int* es  = (unsigned int*)(cursor + N);
  int*   bsum    = (int*)(es + E);
  unsigned int* xb0 = (unsigned int*)(bsum + NB);      // N*D packed
  unsigned int* xb1 = xb0 + (size_t)N * D;
  unsigned int* rel_pk = xb1 + (size_t)N * D;          // L*R*D packed

  const int* srcp = edge_index;
  const int* dstp = edge_index + E;

  hipMemsetAsync(x0, 0, (size_t)2 * N * D * sizeof(float), stream);
  hipMemsetAsync(xb0, 0, (size_t)N * D * sizeof(unsigned int), stream);
  hipMemsetAsync(cnt, 0, N * sizeof(int), stream);
  k_init<<<1, 64, 0, stream>>>(rel_reps, h_index, r_index, x0, xb0, query);
  k_rel<<<L * B * R, 64, 0, stream>>>(rel_reps, proj_w1, proj_b1, proj_w2, proj_b2, rel_all);
  k_pack_rel<<<(L * R * D + 255) / 256, 256, 0, stream>>>((const float2*)rel_all, rel_pk);
  k_hist<<<EB, 256, 0, stream>>>(dstp, cnt);
  k_scan1<<<NB, 256, 0, stream>>>(cnt, row_ptr, bsum);
  k_scan2<<<1, 256, 0, stream>>>(bsum, row_ptr);
  k_scan3<<<NB, 256, 0, stream>>>(row_ptr, bsum, cursor);
  k_fill<<<EB, 256, 0, stream>>>(srcp, dstp, edge_type, cursor, es);

  float* xo = x0;  float* xn = x1;
  unsigned int* xbo = xb0;  unsigned int* xbn = xb1;
  for (int l = 0; l < L; ++l) {
    // gather writes agg into xn; linear updates xn in place and writes xbn
    k_gather<<<N / 4, 256, 0, stream>>>(xbo, (float2*)xn,
                                        rel_pk + (size_t)l * R * D,
                                        row_ptr, es, (const float2*)query, h_index,
                                        (l == 0) ? 1 : 0);
    k_linear<<<N / 64, 512, 0, stream>>>((const float2*)xo, (float2*)xn, xbn,
                                         lin_w, lin_b, ln_g, ln_b, l);
    float* t = xo; xo = xn; xn = t;
    unsigned int* tb = xbo; xbo = xbn; xbn = tb;
  }
  k_mlp<<<N / 16, 256, 0, stream>>>(xbo, (const float2*)query,
                                    mlp_w, mlp_b, (float2*)d_out);
}

// Round 9
// 496.120 us; speedup vs baseline: 1.3613x; 1.3613x over previous
//
#include <hip/hip_runtime.h>
#include <hip/hip_bf16.h>

namespace {

constexpr int B = 2;
constexpr int N = 40000;
constexpr int E = 400000;
constexpr int R = 64;
constexpr int D = 64;
constexpr int L = 6;
constexpr float EPS = 1e-5f;
constexpr int NB = (N + 255) / 256;   // 157 node-grid blocks
constexpr int EB = (E + 255) / 256;   // 1563 edge-grid blocks

typedef _Float16 v8h __attribute__((ext_vector_type(8)));
typedef _Float16 v2h __attribute__((ext_vector_type(2)));
typedef float    v4f __attribute__((ext_vector_type(4)));

// Compiler-only memory barrier (TBAA insurance for LDS type-punned reads).
__device__ __forceinline__ void compiler_fence() { asm volatile("" ::: "memory"); }

__device__ __forceinline__ unsigned int pack_h2(float a, float b) {
  v2h p; p.x = (_Float16)a; p.y = (_Float16)b;
  return __builtin_bit_cast(unsigned int, p);
}
__device__ __forceinline__ float2 unpack_h2(unsigned int u) {
  v2h p = __builtin_bit_cast(v2h, u);
  return make_float2((float)p.x, (float)p.y);
}

// Batch-interleaved packed element = (batch0, batch1) f16 in one dword.

// ---- init: query gather + boundary scatter (x2, xb, xrow pre-zeroed) ----
__global__ void k_init(const float* __restrict__ rel_reps,
                       const int* __restrict__ h_index, const int* __restrict__ r_index,
                       float2* __restrict__ x2, unsigned int* __restrict__ xb,
                       _Float16* __restrict__ xrow0, _Float16* __restrict__ xrow1,
                       float* __restrict__ query_f) {
  int d = threadIdx.x;               // 64 threads
  int h0 = h_index[0], h1 = h_index[1];
  float q0 = rel_reps[r_index[0] * D + d];
  float q1 = rel_reps[(R + r_index[1]) * D + d];
  query_f[d * 2] = q0; query_f[d * 2 + 1] = q1;
  // fp32 residual (component writes in case h0 == h1)
  ((float*)&x2[(size_t)h0 * D + d])[0] = q0;
  ((float*)&x2[(size_t)h1 * D + d])[1] = q1;
  if (h0 == h1) {
    xb[(size_t)h0 * D + d] = pack_h2(q0, q1);
  } else {
    xb[(size_t)h0 * D + d] = pack_h2(q0, 0.f);
    xb[(size_t)h1 * D + d] = pack_h2(0.f, q1);
  }
  xrow0[(size_t)h0 * 2 * D + d] = (_Float16)q0;   // x-half of A rows
  xrow1[(size_t)h1 * 2 * D + d] = (_Float16)q1;
}

// ---- relation projection MLP for all layers: rel_f[l][r*64+d] = (b0, b1) fp32 ----
__global__ __launch_bounds__(64) void k_rel(
    const float* __restrict__ rel_reps,
    const float* __restrict__ pw1, const float* __restrict__ pb1,
    const float* __restrict__ pw2, const float* __restrict__ pb2,
    float* __restrict__ rel_f) {
  __shared__ float row[D];
  __shared__ float row2[D];
  int idx = blockIdx.x;             // [0, L*B*R)
  int l = idx / (B * R);
  int br = idx - l * (B * R);       // b*R + r
  int b = br / R, r = br - b * R;
  int d = threadIdx.x;
  row[d] = rel_reps[(size_t)br * D + d];
  __syncthreads();
  const float* w1 = pw1 + (size_t)l * D * D;
  float acc = pb1[l * D + d];
  for (int k = 0; k < D; ++k) acc = fmaf(row[k], w1[k * D + d], acc);
  row2[d] = fmaxf(acc, 0.f);
  __syncthreads();
  const float* w2 = pw2 + (size_t)l * D * D;
  float acc2 = pb2[l * D + d];
  for (int k = 0; k < D; ++k) acc2 = fmaf(row2[k], w2[k * D + d], acc2);
  rel_f[(((size_t)l * R + r) * D + d) * 2 + b] = acc2;
}

// pack rel fp32-float2 -> f16x2 dword (L*R*D entries)
__global__ __launch_bounds__(256) void k_pack_rel(const float2* __restrict__ rel2,
                                                  unsigned int* __restrict__ rel_pk) {
  int i = blockIdx.x * 256 + threadIdx.x;
  if (i < L * R * D) {
    float2 v = rel2[i];
    rel_pk[i] = pack_h2(v.x, v.y);
  }
}

// pack lin_w fp32 -> f16 MFMA B-fragments, fragment-contiguous.
// Wf[l*8192 + ((ct*4+ks)*64 + lane)*8 + j] = f16(lin_w[l][k][n]),
//   k = ks*32 + (lane>>4)*8 + j, n = ct*16 + (lane&15).
__global__ __launch_bounds__(64) void k_pack_w(const float* __restrict__ lin_w,
                                               unsigned short* __restrict__ Wf) {
  int idx = blockIdx.x;             // [0, L*16)
  int l = idx >> 4;
  int ct = (idx >> 2) & 3, ks = idx & 3;
  int lane = threadIdx.x;
  int n = ct * 16 + (lane & 15);
  #pragma unroll
  for (int j = 0; j < 8; ++j) {
    int k = ks * 32 + (lane >> 4) * 8 + j;
    _Float16 v = (_Float16)lin_w[(size_t)l * 2 * D * D + (size_t)k * D + n];
    Wf[(size_t)l * 8192 + ((size_t)(ct * 4 + ks) * 64 + lane) * 8 + j] =
        __builtin_bit_cast(unsigned short, v);
  }
}

// ---- CSR build ----
__global__ __launch_bounds__(256) void k_hist(const int* __restrict__ dst,
                                              int* __restrict__ cnt) {
  int e = blockIdx.x * 256 + threadIdx.x;
  if (e < E) atomicAdd(&cnt[dst[e]], 1);
}

__global__ __launch_bounds__(256) void k_scan1(const int* __restrict__ cnt,
                                               int* __restrict__ row_ptr,
                                               int* __restrict__ bsum) {
  __shared__ int s[256];
  int t = threadIdx.x;
  int i = blockIdx.x * 256 + t;
  int v = (i < N) ? cnt[i] : 0;
  s[t] = v;
  __syncthreads();
  #pragma unroll
  for (int off = 1; off < 256; off <<= 1) {   // Hillis-Steele inclusive
    int u = (t >= off) ? s[t - off] : 0;
    __syncthreads();
    s[t] += u;
    __syncthreads();
  }
  if (i < N) row_ptr[i] = s[t] - v;           // exclusive-in-block
  if (t == 255) bsum[blockIdx.x] = s[255];
}

__global__ __launch_bounds__(256) void k_scan2(int* __restrict__ bsum,
                                               int* __restrict__ row_ptr) {
  __shared__ int s[NB];
  int t = threadIdx.x;
  if (t < NB) s[t] = bsum[t];
  __syncthreads();
  if (t == 0) {
    int run = 0;
    for (int i = 0; i < NB; ++i) { int v = s[i]; s[i] = run; run += v; }
    row_ptr[N] = run;                         // = E
  }
  __syncthreads();
  if (t < NB) bsum[t] = s[t];
}

__global__ __launch_bounds__(256) void k_scan3(int* __restrict__ row_ptr,
                                               const int* __restrict__ bsum,
                                               int* __restrict__ cursor) {
  int i = blockIdx.x * 256 + threadIdx.x;
  if (i < N) {
    int v = row_ptr[i] + bsum[blockIdx.x];
    row_ptr[i] = v;
    cursor[i] = v;
  }
}

__global__ __launch_bounds__(256) void k_fill(const int* __restrict__ src,
                                              const int* __restrict__ dst,
                                              const int* __restrict__ etype,
                                              int* __restrict__ cursor,
                                              unsigned int* __restrict__ es) {
  int e = blockIdx.x * 256 + threadIdx.x;
  if (e < E) {
    int p = atomicAdd(&cursor[dst[e]], 1);
    es[p] = (unsigned int)src[e] | ((unsigned int)etype[e] << 16);  // src < 65536
  }
}

// ---- gather: one wave per node; f16-packed x (one dword/edge/lane) +
// LDS-staged f16 rel (16 KB). fp32 accumulation. Writes agg-half of xrow (f16).
__global__ __launch_bounds__(256, 8) void k_gather(
    const unsigned int* __restrict__ xb,
    _Float16* __restrict__ xrow0, _Float16* __restrict__ xrow1,
    const unsigned int* __restrict__ rel_pk,     // [R*D] this layer, packed
    const int* __restrict__ row_ptr, const unsigned int* __restrict__ es,
    const float2* __restrict__ q2, const int* __restrict__ h_index, int first) {
  __shared__ unsigned int rel_lds[R * D];        // 16 KB
  int tid = threadIdx.x;
  for (int i = tid; i < R * D; i += 256) rel_lds[i] = rel_pk[i];
  __syncthreads();
  int lane = tid & 63;
  int n = (blockIdx.x * 256 + tid) >> 6;         // node; grid covers N exactly
  int h0 = h_index[0], h1 = h_index[1];
  int rs = row_ptr[n], re = row_ptr[n + 1];
  int m = min(re - rs, 64);
  unsigned int pkl = 0;
  if (lane < m) pkl = es[rs + lane];             // whole edge list, one load
  float a0 = 0.f, a1 = 0.f;
  if (first) {
    // layer 0: x nonzero only at h0 (.x) and h1 (.y)
    for (int j = 0; j < m; ++j) {
      unsigned int pk = __shfl(pkl, j);
      int s  = (int)(pk & 0xffffu);
      int et = (int)(pk >> 16);
      if (s == h0) { float2 xf = unpack_h2(xb[(size_t)s * D + lane]);
                     float2 rf = unpack_h2(rel_lds[et * D + lane]);
                     a0 = fmaf(xf.x, rf.x, a0); }
      if (s == h1) { float2 xf = unpack_h2(xb[(size_t)s * D + lane]);
                     float2 rf = unpack_h2(rel_lds[et * D + lane]);
                     a1 = fmaf(xf.y, rf.y, a1); }
    }
    for (int jj = rs + 64; jj < re; ++jj) {      // deg>64 overflow (rare)
      unsigned int pk = es[jj];
      int s  = (int)(pk & 0xffffu);
      int et = (int)(pk >> 16);
      if (s == h0) { float2 xf = unpack_h2(xb[(size_t)s * D + lane]);
                     float2 rf = unpack_h2(rel_lds[et * D + lane]);
                     a0 = fmaf(xf.x, rf.x, a0); }
      if (s == h1) { float2 xf = unpack_h2(xb[(size_t)s * D + lane]);
                     float2 rf = unpack_h2(rel_lds[et * D + lane]);
                     a1 = fmaf(xf.y, rf.y, a1); }
    }
  } else {
    int j = 0;
    for (; j + 4 <= m; j += 4) {                 // 4 independent global loads in flight
      unsigned int p0 = __shfl(pkl, j),     p1 = __shfl(pkl, j + 1);
      unsigned int p2 = __shfl(pkl, j + 2), p3 = __shfl(pkl, j + 3);
      unsigned int xa = xb[(size_t)(p0 & 0xffffu) * D + lane];
      unsigned int xbv = xb[(size_t)(p1 & 0xffffu) * D + lane];
      unsigned int xc = xb[(size_t)(p2 & 0xffffu) * D + lane];
      unsigned int xd = xb[(size_t)(p3 & 0xffffu) * D + lane];
      unsigned int ra = rel_lds[(p0 >> 16) * D + lane];
      unsigned int rb = rel_lds[(p1 >> 16) * D + lane];
      unsigned int rc = rel_lds[(p2 >> 16) * D + lane];
      unsigned int rd = rel_lds[(p3 >> 16) * D + lane];
      float2 xf, rf;
      xf = unpack_h2(xa);  rf = unpack_h2(ra);
      a0 = fmaf(xf.x, rf.x, a0); a1 = fmaf(xf.y, rf.y, a1);
      xf = unpack_h2(xbv); rf = unpack_h2(rb);
      a0 = fmaf(xf.x, rf.x, a0); a1 = fmaf(xf.y, rf.y, a1);
      xf = unpack_h2(xc);  rf = unpack_h2(rc);
      a0 = fmaf(xf.x, rf.x, a0); a1 = fmaf(xf.y, rf.y, a1);
      xf = unpack_h2(xd);  rf = unpack_h2(rd);
      a0 = fmaf(xf.x, rf.x, a0); a1 = fmaf(xf.y, rf.y, a1);
    }
    for (; j < m; ++j) {
      unsigned int pk = __shfl(pkl, j);
      float2 xf = unpack_h2(xb[(size_t)(pk & 0xffffu) * D + lane]);
      float2 rf = unpack_h2(rel_lds[(pk >> 16) * D + lane]);
      a0 = fmaf(xf.x, rf.x, a0); a1 = fmaf(xf.y, rf.y, a1);
    }
    for (int jj = rs + 64; jj < re; ++jj) {      // deg>64 overflow (rare)
      unsigned int pk = es[jj];
      float2 xf = unpack_h2(xb[(size_t)(pk & 0xffffu) * D + lane]);
      float2 rf = unpack_h2(rel_lds[(pk >> 16) * D + lane]);
      a0 = fmaf(xf.x, rf.x, a0); a1 = fmaf(xf.y, rf.y, a1);
    }
  }
  if (n == h0) a0 += q2[lane].x;                 // + boundary (fp32)
  if (n == h1) a1 += q2[lane].y;
  xrow0[(size_t)n * 2 * D + D + lane] = (_Float16)a0;   // agg-half of A rows
  xrow1[(size_t)n * 2 * D + D + lane] = (_Float16)a1;
}

// ---- MFMA linear + LN + relu + shortcut ----
// One wave per 16-node tile, both batches. Zero LDS. Grid 2500 x 64.
// A[m=lane&15][k=(lane>>4)*8+j] from xrow (f16); B preloaded frags (Wf);
// C/D: col=lane&15, row=(lane>>4)*4+reg. fp32 residual x2 updated in place;
// also writes packed xb (for gather/mlp) and x-half of xrow (for next linear).
__global__ __launch_bounds__(64) void k_linear(
    float2* __restrict__ x2, unsigned int* __restrict__ xb,
    _Float16* __restrict__ xrow0, _Float16* __restrict__ xrow1,
    const unsigned short* __restrict__ Wf,
    const float* __restrict__ lin_b, const float* __restrict__ ln_g,
    const float* __restrict__ ln_b, int layer) {
  int lane = threadIdx.x;
  int nb = blockIdx.x * 16;
  int c = lane & 15, rg = lane >> 4;
  // B-fragments (16 x 16 B, L2-hot)
  const v8h* wf = (const v8h*)(Wf + (size_t)layer * 8192);
  v8h Bf[4][4];
  #pragma unroll
  for (int ct = 0; ct < 4; ++ct)
    #pragma unroll
    for (int ks = 0; ks < 4; ++ks)
      Bf[ct][ks] = wf[(ct * 4 + ks) * 64 + lane];
  v4f acc0[4], acc1[4];
  #pragma unroll
  for (int ct = 0; ct < 4; ++ct) {
    acc0[ct] = (v4f){0.f, 0.f, 0.f, 0.f};
    acc1[ct] = (v4f){0.f, 0.f, 0.f, 0.f};
  }
  // K-loop: 4 k-steps x (2 A-loads + 8 MFMA)
  #pragma unroll
  for (int ks = 0; ks < 4; ++ks) {
    size_t aoff = (size_t)(nb + c) * 2 * D + ks * 32 + rg * 8;
    v8h A0 = *(const v8h*)(xrow0 + aoff);
    v8h A1 = *(const v8h*)(xrow1 + aoff);
    #pragma unroll
    for (int ct = 0; ct < 4; ++ct) {
      acc0[ct] = __builtin_amdgcn_mfma_f32_16x16x32_f16(A0, Bf[ct][ks], acc0[ct], 0, 0, 0);
      acc1[ct] = __builtin_amdgcn_mfma_f32_16x16x32_f16(A1, Bf[ct][ks], acc1[ct], 0, 0, 0);
    }
  }
  // epilogue: +bias, LN over 64 outs (16-lane col-group x 4 ct), relu, +x
  float bias4[4], g4[4], be4[4];
  #pragma unroll
  for (int ct = 0; ct < 4; ++ct) {
    int d = ct * 16 + c;
    bias4[ct] = lin_b[layer * D + d];
    g4[ct]    = ln_g[layer * D + d];
    be4[ct]   = ln_b[layer * D + d];
  }
  #pragma unroll
  for (int j = 0; j < 4; ++j) {
    int node = nb + rg * 4 + j;
    float v0[4], v1[4];
    float s10 = 0.f, s20 = 0.f, s11 = 0.f, s21 = 0.f;
    #pragma unroll
    for (int ct = 0; ct < 4; ++ct) {
      v0[ct] = acc0[ct][j] + bias4[ct];
      v1[ct] = acc1[ct][j] + bias4[ct];
      s10 += v0[ct]; s20 += v0[ct] * v0[ct];
      s11 += v1[ct]; s21 += v1[ct] * v1[ct];
    }
    #pragma unroll
    for (int mk = 1; mk < 16; mk <<= 1) {   // reduce over the 16-lane col group
      s10 += __shfl_xor(s10, mk); s20 += __shfl_xor(s20, mk);
      s11 += __shfl_xor(s11, mk); s21 += __shfl_xor(s21, mk);
    }
    float mu0 = s10 * (1.f / D), var0 = s20 * (1.f / D) - mu0 * mu0;
    float mu1 = s11 * (1.f / D), var1 = s21 * (1.f / D) - mu1 * mu1;
    float rs0 = rsqrtf(var0 + EPS), rs1 = rsqrtf(var1 + EPS);
    #pragma unroll
    for (int ct = 0; ct < 4; ++ct) {
      int d = ct * 16 + c;
      float o0 = fmaxf((v0[ct] - mu0) * rs0 * g4[ct] + be4[ct], 0.f);
      float o1 = fmaxf((v1[ct] - mu1) * rs1 * g4[ct] + be4[ct], 0.f);
      float2 xv = x2[(size_t)node * D + d];
      float r0 = o0 + xv.x, r1 = o1 + xv.y;
      x2[(size_t)node * D + d] = make_float2(r0, r1);     // fp32 residual in place
      xb[(size_t)node * D + d] = pack_h2(r0, r1);          // for gather / mlp
      xrow0[(size_t)node * 2 * D + d] = (_Float16)r0;      // x-half for next linear
      xrow1[(size_t)node * 2 * D + d] = (_Float16)r1;
    }
  }
}

// ---- final MLP: relu(concat(x, query) @ mlp_w + mlp_b) -> fp32 out ----
// 256 threads = 4 waves, 4 nodes/wave -> grid 2500; packed-f16 x input.
__global__ __launch_bounds__(256) void k_mlp(
    const unsigned int* __restrict__ xb, const float2* __restrict__ q2,
    const float* __restrict__ mlp_w,            // [2D][2D] row-major fp32
    const float* __restrict__ mlp_b,
    float2* __restrict__ out) {
  __shared__ uint2 wpk[D][D];             // [k2][colpair], f16-packed; 32 KB
  __shared__ unsigned int rowsx[4][4][D]; // packed x half; 4 KB
  __shared__ float2 q2s[D];               // query half fp32
  int tid = threadIdx.x;
  for (int i = tid; i < D * D; i += 256) {
    int k2 = i >> 6, jp = i & 63;
    const float* w0 = mlp_w + (size_t)(2 * k2) * 2 * D;
    const float* w1 = mlp_w + (size_t)(2 * k2 + 1) * 2 * D;
    wpk[k2][jp] = make_uint2(pack_h2(w0[2 * jp], w0[2 * jp + 1]),
                             pack_h2(w1[2 * jp], w1[2 * jp + 1]));
  }
  if (tid < D) q2s[tid] = q2[tid];
  __syncthreads();
  int wid = tid >> 6, lane = tid & 63;
  float b0 = mlp_b[2 * lane], b1 = mlp_b[2 * lane + 1];
  int gbase = blockIdx.x * 16 + wid * 4;     // N = 40000 = 2500 blocks * 16
  #pragma unroll
  for (int ni = 0; ni < 4; ++ni)
    rowsx[wid][ni][lane] = xb[(size_t)(gbase + ni) * D + lane];
  compiler_fence();
  float a00[4], a01[4], a10[4], a11[4];
  #pragma unroll
  for (int ni = 0; ni < 4; ++ni) { a00[ni] = b0; a01[ni] = b1; a10[ni] = b0; a11[ni] = b1; }
  #pragma unroll 4
  for (int k2 = 0; k2 < D / 2; ++k2) {      // x half: rows k = 2k2, 2k2+1
    uint2 wv = wpk[k2][lane];
    float2 we = unpack_h2(wv.x);   // w[2k2][2lane], w[2k2][2lane+1]
    float2 wo = unpack_h2(wv.y);   // w[2k2+1][...]
    #pragma unroll
    for (int ni = 0; ni < 4; ++ni) {
      uint2 xv = ((const uint2*)&rowsx[wid][ni][0])[k2];
      float2 xe = unpack_h2(xv.x);   // k=2k2:   (b0, b1)
      float2 xo = unpack_h2(xv.y);   // k=2k2+1: (b0, b1)
      a00[ni] = fmaf(xe.x, we.x, a00[ni]); a01[ni] = fmaf(xe.x, we.y, a01[ni]);
      a10[ni] = fmaf(xe.y, we.x, a10[ni]); a11[ni] = fmaf(xe.y, we.y, a11[ni]);
      a00[ni] = fmaf(xo.x, wo.x, a00[ni]); a01[ni] = fmaf(xo.x, wo.y, a01[ni]);
      a10[ni] = fmaf(xo.y, wo.x, a10[ni]); a11[ni] = fmaf(xo.y, wo.y, a11[ni]);
    }
  }
  #pragma unroll 4
  for (int k2 = D / 2; k2 < D; ++k2) {      // query half: shared across nodes
    uint2 wv = wpk[k2][lane];
    float2 we = unpack_h2(wv.x);
    float2 wo = unpack_h2(wv.y);
    float4 qq = ((const float4*)q2s)[k2 - D / 2];   // (q_even b0,b1, q_odd b0,b1)
    #pragma unroll
    for (int ni = 0; ni < 4; ++ni) {
      a00[ni] = fmaf(qq.x, we.x, a00[ni]); a01[ni] = fmaf(qq.x, we.y, a01[ni]);
      a10[ni] = fmaf(qq.y, we.x, a10[ni]); a11[ni] = fmaf(qq.y, we.y, a11[ni]);
      a00[ni] = fmaf(qq.z, wo.x, a00[ni]); a01[ni] = fmaf(qq.z, wo.y, a01[ni]);
      a10[ni] = fmaf(qq.w, wo.x, a10[ni]); a11[ni] = fmaf(qq.w, wo.y, a11[ni]);
    }
  }
  #pragma unroll
  for (int ni = 0; ni < 4; ++ni) {
    int n = gbase + ni;
    out[(size_t)n * D + lane] = make_float2(fmaxf(a00[ni], 0.f), fmaxf(a01[ni], 0.f));
    out[((size_t)N + n) * D + lane] = make_float2(fmaxf(a10[ni], 0.f), fmaxf(a11[ni], 0.f));
  }
}

}  // namespace

extern "C" void kernel_launch(void* const* d_in, const int* in_sizes, int n_in,
                              void* d_out, int out_size, void* d_ws, size_t ws_size,
                              hipStream_t stream) {
  const float* rel_reps = (const float*)d_in[0];
  const int* h_index    = (const int*)d_in[1];
  const int* r_index    = (const int*)d_in[2];
  const int* edge_index = (const int*)d_in[3];
  const int* edge_type  = (const int*)d_in[4];
  const float* proj_w1  = (const float*)d_in[5];
  const float* proj_b1  = (const float*)d_in[6];
  const float* proj_w2  = (const float*)d_in[7];
  const float* proj_b2  = (const float*)d_in[8];
  const float* lin_w    = (const float*)d_in[9];
  const float* lin_b    = (const float*)d_in[10];
  const float* ln_g     = (const float*)d_in[11];
  const float* ln_b     = (const float*)d_in[12];
  const float* mlp_w    = (const float*)d_in[13];
  const float* mlp_b    = (const float*)d_in[14];

  // workspace: x2 | rel_all | query | cnt | row_ptr | cursor | es | bsum |
  //            xb | rel_pk | Wf | xrow0 | xrow1
  float* x2f     = (float*)d_ws;                       // N*D float2
  float* rel_all = x2f + (size_t)2 * N * D;            // L*R*D float2
  float* query   = rel_all + (size_t)2 * L * R * D;    // D float2
  int*   cnt     = (int*)(query + 2 * D);
  int*   row_ptr = cnt + N;
  int*   cursor  = row_ptr + (N + 1);
  unsigned int* es  = (unsigned int*)(cursor + N);
  int*   bsum    = (int*)(es + E);
  unsigned int* xb = (unsigned int*)(bsum + NB);       // N*D packed f16x2
  unsigned int* rel_pk = xb + (size_t)N * D;           // L*R*D packed
  unsigned short* Wf = (unsigned short*)(rel_pk + (size_t)L * R * D);  // L*8192
  _Float16* xrow0 = (_Float16*)(Wf + (size_t)L * 8192);  // N*128
  _Float16* xrow1 = xrow0 + (size_t)N * 2 * D;           // N*128

  const int* srcp = edge_index;
  const int* dstp = edge_index + E;

  hipMemsetAsync(x2f, 0, (size_t)2 * N * D * sizeof(float), stream);
  hipMemsetAsync(xb, 0, (size_t)N * D * sizeof(unsigned int), stream);
  hipMemsetAsync(xrow0, 0, (size_t)N * 2 * D * sizeof(_Float16) * 2, stream);  // both rows
  hipMemsetAsync(cnt, 0, N * sizeof(int), stream);
  k_init<<<1, 64, 0, stream>>>(rel_reps, h_index, r_index,
                               (float2*)x2f, xb, xrow0, xrow1, query);
  k_rel<<<L * B * R, 64, 0, stream>>>(rel_reps, proj_w1, proj_b1, proj_w2, proj_b2, rel_all);
  k_pack_rel<<<(L * R * D + 255) / 256, 256, 0, stream>>>((const float2*)rel_all, rel_pk);
  k_pack_w<<<L * 16, 64, 0, stream>>>(lin_w, Wf);
  k_hist<<<EB, 256, 0, stream>>>(dstp, cnt);
  k_scan1<<<NB, 256, 0, stream>>>(cnt, row_ptr, bsum);
  k_scan2<<<1, 256, 0, stream>>>(bsum, row_ptr);
  k_scan3<<<NB, 256, 0, stream>>>(row_ptr, bsum, cursor);
  k_fill<<<EB, 256, 0, stream>>>(srcp, dstp, edge_type, cursor, es);

  for (int l = 0; l < L; ++l) {
    k_gather<<<N / 4, 256, 0, stream>>>(xb, xrow0, xrow1,
                                        rel_pk + (size_t)l * R * D,
                                        row_ptr, es, (const float2*)query, h_index,
                                        (l == 0) ? 1 : 0);
    k_linear<<<N / 16, 64, 0, stream>>>((float2*)x2f, xb, xrow0, xrow1,
                                        Wf, lin_b, ln_g, ln_b, l);
  }
  k_mlp<<<N / 16, 256, 0, stream>>>(xb, (const float2*)query,
                                    mlp_w, mlp_b, (float2*)d_out);
}

// Round 10
// 430.279 us; speedup vs baseline: 1.5695x; 1.1530x over previous
//
#include <hip/hip_runtime.h>
#include <hip/hip_bf16.h>

namespace {

constexpr int B = 2;
constexpr int N = 40000;
constexpr int E = 400000;
constexpr int R = 64;
constexpr int D = 64;
constexpr int L = 6;
constexpr float EPS = 1e-5f;
constexpr int NB = (N + 255) / 256;   // 157 node-grid blocks
constexpr int EB = (E + 255) / 256;   // 1563 edge-grid blocks

typedef _Float16 v8h __attribute__((ext_vector_type(8)));
typedef _Float16 v2h __attribute__((ext_vector_type(2)));
typedef float    v4f __attribute__((ext_vector_type(4)));

__device__ __forceinline__ unsigned int pack_h2(float a, float b) {
  v2h p; p.x = (_Float16)a; p.y = (_Float16)b;
  return __builtin_bit_cast(unsigned int, p);
}
__device__ __forceinline__ float2 unpack_h2(unsigned int u) {
  v2h p = __builtin_bit_cast(v2h, u);
  return make_float2((float)p.x, (float)p.y);
}

// Batch-interleaved packed element = (batch0, batch1) f16 in one dword.

// ---- init: query gather + boundary scatter (x2, xb, xrow pre-zeroed) ----
__global__ void k_init(const float* __restrict__ rel_reps,
                       const int* __restrict__ h_index, const int* __restrict__ r_index,
                       float2* __restrict__ x2, unsigned int* __restrict__ xb,
                       _Float16* __restrict__ xrow0, _Float16* __restrict__ xrow1,
                       float* __restrict__ query_f, _Float16* __restrict__ qh) {
  int d = threadIdx.x;               // 64 threads
  int h0 = h_index[0], h1 = h_index[1];
  float q0 = rel_reps[r_index[0] * D + d];
  float q1 = rel_reps[(R + r_index[1]) * D + d];
  query_f[d * 2] = q0; query_f[d * 2 + 1] = q1;
  qh[d]     = (_Float16)q0;          // f16 query, per batch (for k_mlp A-frags)
  qh[D + d] = (_Float16)q1;
  // fp32 residual (component writes in case h0 == h1)
  ((float*)&x2[(size_t)h0 * D + d])[0] = q0;
  ((float*)&x2[(size_t)h1 * D + d])[1] = q1;
  if (h0 == h1) {
    xb[(size_t)h0 * D + d] = pack_h2(q0, q1);
  } else {
    xb[(size_t)h0 * D + d] = pack_h2(q0, 0.f);
    xb[(size_t)h1 * D + d] = pack_h2(0.f, q1);
  }
  xrow0[(size_t)h0 * 2 * D + d] = (_Float16)q0;   // x-half of A rows
  xrow1[(size_t)h1 * 2 * D + d] = (_Float16)q1;
}

// ---- relation projection MLP for all layers: rel_f[l][r*64+d] = (b0, b1) fp32 ----
__global__ __launch_bounds__(64) void k_rel(
    const float* __restrict__ rel_reps,
    const float* __restrict__ pw1, const float* __restrict__ pb1,
    const float* __restrict__ pw2, const float* __restrict__ pb2,
    float* __restrict__ rel_f) {
  __shared__ float row[D];
  __shared__ float row2[D];
  int idx = blockIdx.x;             // [0, L*B*R)
  int l = idx / (B * R);
  int br = idx - l * (B * R);       // b*R + r
  int b = br / R, r = br - b * R;
  int d = threadIdx.x;
  row[d] = rel_reps[(size_t)br * D + d];
  __syncthreads();
  const float* w1 = pw1 + (size_t)l * D * D;
  float acc = pb1[l * D + d];
  for (int k = 0; k < D; ++k) acc = fmaf(row[k], w1[k * D + d], acc);
  row2[d] = fmaxf(acc, 0.f);
  __syncthreads();
  const float* w2 = pw2 + (size_t)l * D * D;
  float acc2 = pb2[l * D + d];
  for (int k = 0; k < D; ++k) acc2 = fmaf(row2[k], w2[k * D + d], acc2);
  rel_f[(((size_t)l * R + r) * D + d) * 2 + b] = acc2;
}

// pack rel fp32-float2 -> f16x2 dword (L*R*D entries)
__global__ __launch_bounds__(256) void k_pack_rel(const float2* __restrict__ rel2,
                                                  unsigned int* __restrict__ rel_pk) {
  int i = blockIdx.x * 256 + threadIdx.x;
  if (i < L * R * D) {
    float2 v = rel2[i];
    rel_pk[i] = pack_h2(v.x, v.y);
  }
}

// pack lin_w fp32 -> f16 MFMA B-fragments, fragment-contiguous.
// Wf[l*8192 + ((ct*4+ks)*64 + lane)*8 + j] = f16(lin_w[l][k][n]),
//   k = ks*32 + (lane>>4)*8 + j, n = ct*16 + (lane&15).
__global__ __launch_bounds__(64) void k_pack_w(const float* __restrict__ lin_w,
                                               unsigned short* __restrict__ Wf) {
  int idx = blockIdx.x;             // [0, L*16)
  int l = idx >> 4;
  int ct = (idx >> 2) & 3, ks = idx & 3;
  int lane = threadIdx.x;
  int n = ct * 16 + (lane & 15);
  #pragma unroll
  for (int j = 0; j < 8; ++j) {
    int k = ks * 32 + (lane >> 4) * 8 + j;
    _Float16 v = (_Float16)lin_w[(size_t)l * 2 * D * D + (size_t)k * D + n];
    Wf[(size_t)l * 8192 + ((size_t)(ct * 4 + ks) * 64 + lane) * 8 + j] =
        __builtin_bit_cast(unsigned short, v);
  }
}

// pack mlp_w fp32 [128][128] -> f16 MFMA B-fragments (8 ct x 4 ks).
// Wm[((ct*4+ks)*64 + lane)*8 + j] = f16(mlp_w[k][n]),
//   k = ks*32 + (lane>>4)*8 + j, n = ct*16 + (lane&15).
__global__ __launch_bounds__(64) void k_pack_wm(const float* __restrict__ mlp_w,
                                                unsigned short* __restrict__ Wm) {
  int idx = blockIdx.x;             // [0, 32): ct = idx>>2, ks = idx&3
  int ct = idx >> 2, ks = idx & 3;
  int lane = threadIdx.x;
  int n = ct * 16 + (lane & 15);
  #pragma unroll
  for (int j = 0; j < 8; ++j) {
    int k = ks * 32 + (lane >> 4) * 8 + j;
    _Float16 v = (_Float16)mlp_w[(size_t)k * 2 * D + n];
    Wm[((size_t)idx * 64 + lane) * 8 + j] = __builtin_bit_cast(unsigned short, v);
  }
}

// ---- CSR build ----
__global__ __launch_bounds__(256) void k_hist(const int* __restrict__ dst,
                                              int* __restrict__ cnt) {
  int e = blockIdx.x * 256 + threadIdx.x;
  if (e < E) atomicAdd(&cnt[dst[e]], 1);
}

__global__ __launch_bounds__(256) void k_scan1(const int* __restrict__ cnt,
                                               int* __restrict__ row_ptr,
                                               int* __restrict__ bsum) {
  __shared__ int s[256];
  int t = threadIdx.x;
  int i = blockIdx.x * 256 + t;
  int v = (i < N) ? cnt[i] : 0;
  s[t] = v;
  __syncthreads();
  #pragma unroll
  for (int off = 1; off < 256; off <<= 1) {   // Hillis-Steele inclusive
    int u = (t >= off) ? s[t - off] : 0;
    __syncthreads();
    s[t] += u;
    __syncthreads();
  }
  if (i < N) row_ptr[i] = s[t] - v;           // exclusive-in-block
  if (t == 255) bsum[blockIdx.x] = s[255];
}

__global__ __launch_bounds__(256) void k_scan2(int* __restrict__ bsum,
                                               int* __restrict__ row_ptr) {
  __shared__ int s[NB];
  int t = threadIdx.x;
  if (t < NB) s[t] = bsum[t];
  __syncthreads();
  if (t == 0) {
    int run = 0;
    for (int i = 0; i < NB; ++i) { int v = s[i]; s[i] = run; run += v; }
    row_ptr[N] = run;                         // = E
  }
  __syncthreads();
  if (t < NB) bsum[t] = s[t];
}

__global__ __launch_bounds__(256) void k_scan3(int* __restrict__ row_ptr,
                                               const int* __restrict__ bsum,
                                               int* __restrict__ cursor) {
  int i = blockIdx.x * 256 + threadIdx.x;
  if (i < N) {
    int v = row_ptr[i] + bsum[blockIdx.x];
    row_ptr[i] = v;
    cursor[i] = v;
  }
}

__global__ __launch_bounds__(256) void k_fill(const int* __restrict__ src,
                                              const int* __restrict__ dst,
                                              const int* __restrict__ etype,
                                              int* __restrict__ cursor,
                                              unsigned int* __restrict__ es) {
  int e = blockIdx.x * 256 + threadIdx.x;
  if (e < E) {
    int p = atomicAdd(&cursor[dst[e]], 1);
    es[p] = (unsigned int)src[e] | ((unsigned int)etype[e] << 16);  // src < 65536
  }
}

// ---- gather: one wave per node; f16-packed x (one dword/edge/lane) +
// LDS-staged f16 rel (16 KB). fp32 accumulation. Writes agg-half of xrow (f16).
// 512 threads = 8 waves/block: 4 blocks/CU = 32 waves, halves rel staging vs 256.
__global__ __launch_bounds__(512, 4) void k_gather(
    const unsigned int* __restrict__ xb,
    _Float16* __restrict__ xrow0, _Float16* __restrict__ xrow1,
    const unsigned int* __restrict__ rel_pk,     // [R*D] this layer, packed
    const int* __restrict__ row_ptr, const unsigned int* __restrict__ es,
    const float2* __restrict__ q2, const int* __restrict__ h_index, int first) {
  __shared__ unsigned int rel_lds[R * D];        // 16 KB
  int tid = threadIdx.x;
  for (int i = tid; i < R * D; i += 512) rel_lds[i] = rel_pk[i];
  __syncthreads();
  int lane = tid & 63;
  int n = (blockIdx.x * 512 + tid) >> 6;         // node; grid covers N exactly
  int h0 = h_index[0], h1 = h_index[1];
  int rs = row_ptr[n], re = row_ptr[n + 1];
  int m = min(re - rs, 64);
  unsigned int pkl = 0;
  if (lane < m) pkl = es[rs + lane];             // whole edge list, one load
  float a0 = 0.f, a1 = 0.f;
  if (first) {
    // layer 0: x nonzero only at h0 (.x) and h1 (.y)
    for (int j = 0; j < m; ++j) {
      unsigned int pk = __shfl(pkl, j);
      int s  = (int)(pk & 0xffffu);
      int et = (int)(pk >> 16);
      if (s == h0) { float2 xf = unpack_h2(xb[(size_t)s * D + lane]);
                     float2 rf = unpack_h2(rel_lds[et * D + lane]);
                     a0 = fmaf(xf.x, rf.x, a0); }
      if (s == h1) { float2 xf = unpack_h2(xb[(size_t)s * D + lane]);
                     float2 rf = unpack_h2(rel_lds[et * D + lane]);
                     a1 = fmaf(xf.y, rf.y, a1); }
    }
    for (int jj = rs + 64; jj < re; ++jj) {      // deg>64 overflow (rare)
      unsigned int pk = es[jj];
      int s  = (int)(pk & 0xffffu);
      int et = (int)(pk >> 16);
      if (s == h0) { float2 xf = unpack_h2(xb[(size_t)s * D + lane]);
                     float2 rf = unpack_h2(rel_lds[et * D + lane]);
                     a0 = fmaf(xf.x, rf.x, a0); }
      if (s == h1) { float2 xf = unpack_h2(xb[(size_t)s * D + lane]);
                     float2 rf = unpack_h2(rel_lds[et * D + lane]);
                     a1 = fmaf(xf.y, rf.y, a1); }
    }
  } else {
    int j = 0;
    for (; j + 4 <= m; j += 4) {                 // 4 independent global loads in flight
      unsigned int p0 = __shfl(pkl, j),     p1 = __shfl(pkl, j + 1);
      unsigned int p2 = __shfl(pkl, j + 2), p3 = __shfl(pkl, j + 3);
      unsigned int xa = xb[(size_t)(p0 & 0xffffu) * D + lane];
      unsigned int xbv = xb[(size_t)(p1 & 0xffffu) * D + lane];
      unsigned int xc = xb[(size_t)(p2 & 0xffffu) * D + lane];
      unsigned int xd = xb[(size_t)(p3 & 0xffffu) * D + lane];
      unsigned int ra = rel_lds[(p0 >> 16) * D + lane];
      unsigned int rb = rel_lds[(p1 >> 16) * D + lane];
      unsigned int rc = rel_lds[(p2 >> 16) * D + lane];
      unsigned int rd = rel_lds[(p3 >> 16) * D + lane];
      float2 xf, rf;
      xf = unpack_h2(xa);  rf = unpack_h2(ra);
      a0 = fmaf(xf.x, rf.x, a0); a1 = fmaf(xf.y, rf.y, a1);
      xf = unpack_h2(xbv); rf = unpack_h2(rb);
      a0 = fmaf(xf.x, rf.x, a0); a1 = fmaf(xf.y, rf.y, a1);
      xf = unpack_h2(xc);  rf = unpack_h2(rc);
      a0 = fmaf(xf.x, rf.x, a0); a1 = fmaf(xf.y, rf.y, a1);
      xf = unpack_h2(xd);  rf = unpack_h2(rd);
      a0 = fmaf(xf.x, rf.x, a0); a1 = fmaf(xf.y, rf.y, a1);
    }
    for (; j < m; ++j) {
      unsigned int pk = __shfl(pkl, j);
      float2 xf = unpack_h2(xb[(size_t)(pk & 0xffffu) * D + lane]);
      float2 rf = unpack_h2(rel_lds[(pk >> 16) * D + lane]);
      a0 = fmaf(xf.x, rf.x, a0); a1 = fmaf(xf.y, rf.y, a1);
    }
    for (int jj = rs + 64; jj < re; ++jj) {      // deg>64 overflow (rare)
      unsigned int pk = es[jj];
      float2 xf = unpack_h2(xb[(size_t)(pk & 0xffffu) * D + lane]);
      float2 rf = unpack_h2(rel_lds[(pk >> 16) * D + lane]);
      a0 = fmaf(xf.x, rf.x, a0); a1 = fmaf(xf.y, rf.y, a1);
    }
  }
  if (n == h0) a0 += q2[lane].x;                 // + boundary (fp32)
  if (n == h1) a1 += q2[lane].y;
  xrow0[(size_t)n * 2 * D + D + lane] = (_Float16)a0;   // agg-half of A rows
  xrow1[(size_t)n * 2 * D + D + lane] = (_Float16)a1;
}

// ---- MFMA linear + LN + relu + shortcut ----
// One wave per 16-node tile, both batches. Zero LDS. Grid 2500 x 64.
__global__ __launch_bounds__(64) void k_linear(
    float2* __restrict__ x2, unsigned int* __restrict__ xb,
    _Float16* __restrict__ xrow0, _Float16* __restrict__ xrow1,
    const unsigned short* __restrict__ Wf,
    const float* __restrict__ lin_b, const float* __restrict__ ln_g,
    const float* __restrict__ ln_b, int layer) {
  int lane = threadIdx.x;
  int nb = blockIdx.x * 16;
  int c = lane & 15, rg = lane >> 4;
  // B-fragments (16 x 16 B, L2-hot)
  const v8h* wf = (const v8h*)(Wf + (size_t)layer * 8192);
  v8h Bf[4][4];
  #pragma unroll
  for (int ct = 0; ct < 4; ++ct)
    #pragma unroll
    for (int ks = 0; ks < 4; ++ks)
      Bf[ct][ks] = wf[(ct * 4 + ks) * 64 + lane];
  v4f acc0[4], acc1[4];
  #pragma unroll
  for (int ct = 0; ct < 4; ++ct) {
    acc0[ct] = (v4f){0.f, 0.f, 0.f, 0.f};
    acc1[ct] = (v4f){0.f, 0.f, 0.f, 0.f};
  }
  // K-loop: 4 k-steps x (2 A-loads + 8 MFMA)
  #pragma unroll
  for (int ks = 0; ks < 4; ++ks) {
    size_t aoff = (size_t)(nb + c) * 2 * D + ks * 32 + rg * 8;
    v8h A0 = *(const v8h*)(xrow0 + aoff);
    v8h A1 = *(const v8h*)(xrow1 + aoff);
    #pragma unroll
    for (int ct = 0; ct < 4; ++ct) {
      acc0[ct] = __builtin_amdgcn_mfma_f32_16x16x32_f16(A0, Bf[ct][ks], acc0[ct], 0, 0, 0);
      acc1[ct] = __builtin_amdgcn_mfma_f32_16x16x32_f16(A1, Bf[ct][ks], acc1[ct], 0, 0, 0);
    }
  }
  // epilogue: +bias, LN over 64 outs (16-lane col-group x 4 ct), relu, +x
  float bias4[4], g4[4], be4[4];
  #pragma unroll
  for (int ct = 0; ct < 4; ++ct) {
    int d = ct * 16 + c;
    bias4[ct] = lin_b[layer * D + d];
    g4[ct]    = ln_g[layer * D + d];
    be4[ct]   = ln_b[layer * D + d];
  }
  #pragma unroll
  for (int j = 0; j < 4; ++j) {
    int node = nb + rg * 4 + j;
    float v0[4], v1[4];
    float s10 = 0.f, s20 = 0.f, s11 = 0.f, s21 = 0.f;
    #pragma unroll
    for (int ct = 0; ct < 4; ++ct) {
      v0[ct] = acc0[ct][j] + bias4[ct];
      v1[ct] = acc1[ct][j] + bias4[ct];
      s10 += v0[ct]; s20 += v0[ct] * v0[ct];
      s11 += v1[ct]; s21 += v1[ct] * v1[ct];
    }
    #pragma unroll
    for (int mk = 1; mk < 16; mk <<= 1) {   // reduce over the 16-lane col group
      s10 += __shfl_xor(s10, mk); s20 += __shfl_xor(s20, mk);
      s11 += __shfl_xor(s11, mk); s21 += __shfl_xor(s21, mk);
    }
    float mu0 = s10 * (1.f / D), var0 = s20 * (1.f / D) - mu0 * mu0;
    float mu1 = s11 * (1.f / D), var1 = s21 * (1.f / D) - mu1 * mu1;
    float rs0 = rsqrtf(var0 + EPS), rs1 = rsqrtf(var1 + EPS);
    #pragma unroll
    for (int ct = 0; ct < 4; ++ct) {
      int d = ct * 16 + c;
      float o0 = fmaxf((v0[ct] - mu0) * rs0 * g4[ct] + be4[ct], 0.f);
      float o1 = fmaxf((v1[ct] - mu1) * rs1 * g4[ct] + be4[ct], 0.f);
      float2 xv = x2[(size_t)node * D + d];
      float r0 = o0 + xv.x, r1 = o1 + xv.y;
      x2[(size_t)node * D + d] = make_float2(r0, r1);     // fp32 residual in place
      xb[(size_t)node * D + d] = pack_h2(r0, r1);          // for gather
      xrow0[(size_t)node * 2 * D + d] = (_Float16)r0;      // x-half for next linear/mlp
      xrow1[(size_t)node * 2 * D + d] = (_Float16)r1;
    }
  }
}

// ---- MFMA final MLP: relu([x, query] @ mlp_w + mlp_b) -> fp32 out ----
// One wave per 16-node tile, both batches. A x-half from xrow; A query-half
// node-invariant from f16 query. B frags loaded in-loop (32 KB, L2-hot).
__global__ __launch_bounds__(64) void k_mlp(
    const _Float16* __restrict__ xrow0, const _Float16* __restrict__ xrow1,
    const _Float16* __restrict__ qh,            // [2][64] f16
    const unsigned short* __restrict__ Wm,      // 32 fragments
    const float* __restrict__ mlp_b,
    float* __restrict__ outf) {
  int lane = threadIdx.x;
  int nb = blockIdx.x * 16;
  int c = lane & 15, rg = lane >> 4;
  const v8h* wm = (const v8h*)Wm;
  v4f acc0[8], acc1[8];
  #pragma unroll
  for (int ct = 0; ct < 8; ++ct) {
    acc0[ct] = (v4f){0.f, 0.f, 0.f, 0.f};
    acc1[ct] = (v4f){0.f, 0.f, 0.f, 0.f};
  }
  #pragma unroll
  for (int ks = 0; ks < 4; ++ks) {
    v8h A0, A1;
    if (ks < 2) {                       // x half: k = ks*32 + rg*8 + j in [0,64)
      size_t aoff = (size_t)(nb + c) * 2 * D + ks * 32 + rg * 8;
      A0 = *(const v8h*)(xrow0 + aoff);
      A1 = *(const v8h*)(xrow1 + aoff);
    } else {                            // query half: node-invariant
      int qoff = (ks - 2) * 32 + rg * 8;
      A0 = *(const v8h*)(qh + qoff);
      A1 = *(const v8h*)(qh + D + qoff);
    }
    #pragma unroll
    for (int ct = 0; ct < 8; ++ct) {
      v8h Bv = wm[(ct * 4 + ks) * 64 + lane];
      acc0[ct] = __builtin_amdgcn_mfma_f32_16x16x32_f16(A0, Bv, acc0[ct], 0, 0, 0);
      acc1[ct] = __builtin_amdgcn_mfma_f32_16x16x32_f16(A1, Bv, acc1[ct], 0, 0, 0);
    }
  }
  // epilogue: +bias, relu, store. out flat = [2][N][128] fp32.
  #pragma unroll
  for (int ct = 0; ct < 8; ++ct) {
    int d = ct * 16 + c;
    float bias = mlp_b[d];
    #pragma unroll
    for (int j = 0; j < 4; ++j) {
      int node = nb + rg * 4 + j;
      outf[(size_t)node * 2 * D + d]              = fmaxf(acc0[ct][j] + bias, 0.f);
      outf[((size_t)N + node) * 2 * D + d]        = fmaxf(acc1[ct][j] + bias, 0.f);
    }
  }
}

}  // namespace

extern "C" void kernel_launch(void* const* d_in, const int* in_sizes, int n_in,
                              void* d_out, int out_size, void* d_ws, size_t ws_size,
                              hipStream_t stream) {
  const float* rel_reps = (const float*)d_in[0];
  const int* h_index    = (const int*)d_in[1];
  const int* r_index    = (const int*)d_in[2];
  const int* edge_index = (const int*)d_in[3];
  const int* edge_type  = (const int*)d_in[4];
  const float* proj_w1  = (const float*)d_in[5];
  const float* proj_b1  = (const float*)d_in[6];
  const float* proj_w2  = (const float*)d_in[7];
  const float* proj_b2  = (const float*)d_in[8];
  const float* lin_w    = (const float*)d_in[9];
  const float* lin_b    = (const float*)d_in[10];
  const float* ln_g     = (const float*)d_in[11];
  const float* ln_b     = (const float*)d_in[12];
  const float* mlp_w    = (const float*)d_in[13];
  const float* mlp_b    = (const float*)d_in[14];

  // workspace: x2 | rel_all | query | cnt | row_ptr | cursor | es | bsum |
  //            xb | rel_pk | Wf | xrow0 | xrow1 | Wm | qh
  float* x2f     = (float*)d_ws;                       // N*D float2
  float* rel_all = x2f + (size_t)2 * N * D;            // L*R*D float2
  float* query   = rel_all + (size_t)2 * L * R * D;    // D float2
  int*   cnt     = (int*)(query + 2 * D);
  int*   row_ptr = cnt + N;
  int*   cursor  = row_ptr + (N + 1);
  unsigned int* es  = (unsigned int*)(cursor + N);
  int*   bsum    = (int*)(es + E);
  unsigned int* xb = (unsigned int*)(bsum + NB);       // N*D packed f16x2
  unsigned int* rel_pk = xb + (size_t)N * D;           // L*R*D packed
  unsigned short* Wf = (unsigned short*)(rel_pk + (size_t)L * R * D);  // L*8192
  _Float16* xrow0 = (_Float16*)(Wf + (size_t)L * 8192);  // N*128
  _Float16* xrow1 = xrow0 + (size_t)N * 2 * D;           // N*128
  unsigned short* Wm = (unsigned short*)(xrow1 + (size_t)N * 2 * D);  // 16384
  _Float16* qh = (_Float16*)(Wm + 16384);                // 128

  const int* srcp = edge_index;
  const int* dstp = edge_index + E;

  hipMemsetAsync(x2f, 0, (size_t)2 * N * D * sizeof(float), stream);
  hipMemsetAsync(xb, 0, (size_t)N * D * sizeof(unsigned int), stream);
  hipMemsetAsync(xrow0, 0, (size_t)N * 2 * D * sizeof(_Float16) * 2, stream);  // both rows
  hipMemsetAsync(cnt, 0, N * sizeof(int), stream);
  k_init<<<1, 64, 0, stream>>>(rel_reps, h_index, r_index,
                               (float2*)x2f, xb, xrow0, xrow1, query, qh);
  k_rel<<<L * B * R, 64, 0, stream>>>(rel_reps, proj_w1, proj_b1, proj_w2, proj_b2, rel_all);
  k_pack_rel<<<(L * R * D + 255) / 256, 256, 0, stream>>>((const float2*)rel_all, rel_pk);
  k_pack_w<<<L * 16, 64, 0, stream>>>(lin_w, Wf);
  k_pack_wm<<<32, 64, 0, stream>>>(mlp_w, Wm);
  k_hist<<<EB, 256, 0, stream>>>(dstp, cnt);
  k_scan1<<<NB, 256, 0, stream>>>(cnt, row_ptr, bsum);
  k_scan2<<<1, 256, 0, stream>>>(bsum, row_ptr);
  k_scan3<<<NB, 256, 0, stream>>>(row_ptr, bsum, cursor);
  k_fill<<<EB, 256, 0, stream>>>(srcp, dstp, edge_type, cursor, es);

  for (int l = 0; l < L; ++l) {
    k_gather<<<N / 8, 512, 0, stream>>>(xb, xrow0, xrow1,
                                        rel_pk + (size_t)l * R * D,
                                        row_ptr, es, (const float2*)query, h_index,
                                        (l == 0) ? 1 : 0);
    k_linear<<<N / 16, 64, 0, stream>>>((float2*)x2f, xb, xrow0, xrow1,
                                        Wf, lin_b, ln_g, ln_b, l);
  }
  k_mlp<<<N / 16, 64, 0, stream>>>(xrow0, xrow1, qh, Wm, mlp_b, (float*)d_out);
}

// Round 11
// 393.480 us; speedup vs baseline: 1.7163x; 1.0935x over previous
//
#include <hip/hip_runtime.h>
#include <hip/hip_bf16.h>

namespace {

constexpr int B = 2;
constexpr int N = 40000;
constexpr int E = 400000;
constexpr int R = 64;
constexpr int D = 64;
constexpr int L = 6;
constexpr float EPS = 1e-5f;
constexpr int NB = (N + 255) / 256;   // 157 node-grid blocks
constexpr int EB = (E + 255) / 256;   // 1563 edge-grid blocks

typedef _Float16 v8h __attribute__((ext_vector_type(8)));
typedef _Float16 v2h __attribute__((ext_vector_type(2)));
typedef float    v4f __attribute__((ext_vector_type(4)));

__device__ __forceinline__ unsigned int pack_h2(float a, float b) {
  v2h p; p.x = (_Float16)a; p.y = (_Float16)b;
  return __builtin_bit_cast(unsigned int, p);
}
__device__ __forceinline__ float2 unpack_h2(unsigned int u) {
  v2h p = __builtin_bit_cast(v2h, u);
  return make_float2((float)p.x, (float)p.y);
}

// Batch-interleaved packed element = (batch0, batch1) f16 in one dword.

// ---- init: query gather + boundary scatter (xb, xrow pre-zeroed) ----
__global__ void k_init(const float* __restrict__ rel_reps,
                       const int* __restrict__ h_index, const int* __restrict__ r_index,
                       unsigned int* __restrict__ xb,
                       _Float16* __restrict__ xrow0, _Float16* __restrict__ xrow1,
                       float* __restrict__ query_f, _Float16* __restrict__ qh) {
  int d = threadIdx.x;               // 64 threads
  int h0 = h_index[0], h1 = h_index[1];
  float q0 = rel_reps[r_index[0] * D + d];
  float q1 = rel_reps[(R + r_index[1]) * D + d];
  query_f[d * 2] = q0; query_f[d * 2 + 1] = q1;
  qh[d]     = (_Float16)q0;          // f16 query, per batch (for k_mlp A-frags)
  qh[D + d] = (_Float16)q1;
  if (h0 == h1) {
    xb[(size_t)h0 * D + d] = pack_h2(q0, q1);
  } else {
    xb[(size_t)h0 * D + d] = pack_h2(q0, 0.f);
    xb[(size_t)h1 * D + d] = pack_h2(0.f, q1);
  }
  xrow0[(size_t)h0 * 2 * D + d] = (_Float16)q0;   // x-half of A rows
  xrow1[(size_t)h1 * 2 * D + d] = (_Float16)q1;
}

// ---- relation projection MLP for all layers: rel_f[l][r*64+d] = (b0, b1) fp32 ----
__global__ __launch_bounds__(64) void k_rel(
    const float* __restrict__ rel_reps,
    const float* __restrict__ pw1, const float* __restrict__ pb1,
    const float* __restrict__ pw2, const float* __restrict__ pb2,
    float* __restrict__ rel_f) {
  __shared__ float row[D];
  __shared__ float row2[D];
  int idx = blockIdx.x;             // [0, L*B*R)
  int l = idx / (B * R);
  int br = idx - l * (B * R);       // b*R + r
  int b = br / R, r = br - b * R;
  int d = threadIdx.x;
  row[d] = rel_reps[(size_t)br * D + d];
  __syncthreads();
  const float* w1 = pw1 + (size_t)l * D * D;
  float acc = pb1[l * D + d];
  for (int k = 0; k < D; ++k) acc = fmaf(row[k], w1[k * D + d], acc);
  row2[d] = fmaxf(acc, 0.f);
  __syncthreads();
  const float* w2 = pw2 + (size_t)l * D * D;
  float acc2 = pb2[l * D + d];
  for (int k = 0; k < D; ++k) acc2 = fmaf(row2[k], w2[k * D + d], acc2);
  rel_f[(((size_t)l * R + r) * D + d) * 2 + b] = acc2;
}

// pack rel fp32-float2 -> f16x2 dword (L*R*D entries)
__global__ __launch_bounds__(256) void k_pack_rel(const float2* __restrict__ rel2,
                                                  unsigned int* __restrict__ rel_pk) {
  int i = blockIdx.x * 256 + threadIdx.x;
  if (i < L * R * D) {
    float2 v = rel2[i];
    rel_pk[i] = pack_h2(v.x, v.y);
  }
}

// pack lin_w fp32 -> f16 MFMA B-fragments, fragment-contiguous.
__global__ __launch_bounds__(64) void k_pack_w(const float* __restrict__ lin_w,
                                               unsigned short* __restrict__ Wf) {
  int idx = blockIdx.x;             // [0, L*16)
  int l = idx >> 4;
  int ct = (idx >> 2) & 3, ks = idx & 3;
  int lane = threadIdx.x;
  int n = ct * 16 + (lane & 15);
  #pragma unroll
  for (int j = 0; j < 8; ++j) {
    int k = ks * 32 + (lane >> 4) * 8 + j;
    _Float16 v = (_Float16)lin_w[(size_t)l * 2 * D * D + (size_t)k * D + n];
    Wf[(size_t)l * 8192 + ((size_t)(ct * 4 + ks) * 64 + lane) * 8 + j] =
        __builtin_bit_cast(unsigned short, v);
  }
}

// pack mlp_w fp32 [128][128] -> f16 MFMA B-fragments (8 ct x 4 ks).
__global__ __launch_bounds__(64) void k_pack_wm(const float* __restrict__ mlp_w,
                                                unsigned short* __restrict__ Wm) {
  int idx = blockIdx.x;             // [0, 32): ct = idx>>2, ks = idx&3
  int ct = idx >> 2, ks = idx & 3;
  int lane = threadIdx.x;
  int n = ct * 16 + (lane & 15);
  #pragma unroll
  for (int j = 0; j < 8; ++j) {
    int k = ks * 32 + (lane >> 4) * 8 + j;
    _Float16 v = (_Float16)mlp_w[(size_t)k * 2 * D + n];
    Wm[((size_t)idx * 64 + lane) * 8 + j] = __builtin_bit_cast(unsigned short, v);
  }
}

// ---- CSR build ----
__global__ __launch_bounds__(256) void k_hist(const int* __restrict__ dst,
                                              int* __restrict__ cnt) {
  int e = blockIdx.x * 256 + threadIdx.x;
  if (e < E) atomicAdd(&cnt[dst[e]], 1);
}

__global__ __launch_bounds__(256) void k_scan1(const int* __restrict__ cnt,
                                               int* __restrict__ row_ptr,
                                               int* __restrict__ bsum) {
  __shared__ int s[256];
  int t = threadIdx.x;
  int i = blockIdx.x * 256 + t;
  int v = (i < N) ? cnt[i] : 0;
  s[t] = v;
  __syncthreads();
  #pragma unroll
  for (int off = 1; off < 256; off <<= 1) {   // Hillis-Steele inclusive
    int u = (t >= off) ? s[t - off] : 0;
    __syncthreads();
    s[t] += u;
    __syncthreads();
  }
  if (i < N) row_ptr[i] = s[t] - v;           // exclusive-in-block
  if (t == 255) bsum[blockIdx.x] = s[255];
}

__global__ __launch_bounds__(256) void k_scan2(int* __restrict__ bsum,
                                               int* __restrict__ row_ptr) {
  __shared__ int s[NB];
  int t = threadIdx.x;
  if (t < NB) s[t] = bsum[t];
  __syncthreads();
  if (t == 0) {
    int run = 0;
    for (int i = 0; i < NB; ++i) { int v = s[i]; s[i] = run; run += v; }
    row_ptr[N] = run;                         // = E
  }
  __syncthreads();
  if (t < NB) bsum[t] = s[t];
}

__global__ __launch_bounds__(256) void k_scan3(int* __restrict__ row_ptr,
                                               const int* __restrict__ bsum,
                                               int* __restrict__ cursor) {
  int i = blockIdx.x * 256 + threadIdx.x;
  if (i < N) {
    int v = row_ptr[i] + bsum[blockIdx.x];
    row_ptr[i] = v;
    cursor[i] = v;
  }
}

__global__ __launch_bounds__(256) void k_fill(const int* __restrict__ src,
                                              const int* __restrict__ dst,
                                              const int* __restrict__ etype,
                                              int* __restrict__ cursor,
                                              unsigned int* __restrict__ es) {
  int e = blockIdx.x * 256 + threadIdx.x;
  if (e < E) {
    int p = atomicAdd(&cursor[dst[e]], 1);
    es[p] = (unsigned int)src[e] | ((unsigned int)etype[e] << 16);  // src < 65536
  }
}

// ---- gather: one wave per node; f16-packed x (one dword/edge/lane); rel read
// directly from global (16 KB slice, L1/L2-hot — NO per-block LDS staging).
// fp32 accumulation. Writes agg-half of xrow (f16). Zero LDS, 32 waves/CU.
__global__ __launch_bounds__(256, 8) void k_gather(
    const unsigned int* __restrict__ xb,
    _Float16* __restrict__ xrow0, _Float16* __restrict__ xrow1,
    const unsigned int* __restrict__ rel_pk,     // [R*D] this layer, packed
    const int* __restrict__ row_ptr, const unsigned int* __restrict__ es,
    const float2* __restrict__ q2, const int* __restrict__ h_index, int first) {
  int tid = threadIdx.x;
  int lane = tid & 63;
  int n = (blockIdx.x * 256 + tid) >> 6;         // node; grid covers N exactly
  int h0 = h_index[0], h1 = h_index[1];
  int rs = row_ptr[n], re = row_ptr[n + 1];
  int m = min(re - rs, 64);
  unsigned int pkl = 0;
  if (lane < m) pkl = es[rs + lane];             // whole edge list, one load
  float a0 = 0.f, a1 = 0.f;
  if (first) {
    // layer 0: x nonzero only at h0 (.x) and h1 (.y)
    for (int j = 0; j < m; ++j) {
      unsigned int pk = __shfl(pkl, j);
      int s  = (int)(pk & 0xffffu);
      int et = (int)(pk >> 16);
      if (s == h0) { float2 xf = unpack_h2(xb[(size_t)s * D + lane]);
                     float2 rf = unpack_h2(rel_pk[et * D + lane]);
                     a0 = fmaf(xf.x, rf.x, a0); }
      if (s == h1) { float2 xf = unpack_h2(xb[(size_t)s * D + lane]);
                     float2 rf = unpack_h2(rel_pk[et * D + lane]);
                     a1 = fmaf(xf.y, rf.y, a1); }
    }
    for (int jj = rs + 64; jj < re; ++jj) {      // deg>64 overflow (rare)
      unsigned int pk = es[jj];
      int s  = (int)(pk & 0xffffu);
      int et = (int)(pk >> 16);
      if (s == h0) { float2 xf = unpack_h2(xb[(size_t)s * D + lane]);
                     float2 rf = unpack_h2(rel_pk[et * D + lane]);
                     a0 = fmaf(xf.x, rf.x, a0); }
      if (s == h1) { float2 xf = unpack_h2(xb[(size_t)s * D + lane]);
                     float2 rf = unpack_h2(rel_pk[et * D + lane]);
                     a1 = fmaf(xf.y, rf.y, a1); }
    }
  } else {
    int j = 0;
    for (; j + 4 <= m; j += 4) {                 // 8 independent loads in flight
      unsigned int p0 = __shfl(pkl, j),     p1 = __shfl(pkl, j + 1);
      unsigned int p2 = __shfl(pkl, j + 2), p3 = __shfl(pkl, j + 3);
      unsigned int xa  = xb[(size_t)(p0 & 0xffffu) * D + lane];
      unsigned int xbv = xb[(size_t)(p1 & 0xffffu) * D + lane];
      unsigned int xc  = xb[(size_t)(p2 & 0xffffu) * D + lane];
      unsigned int xd  = xb[(size_t)(p3 & 0xffffu) * D + lane];
      unsigned int ra = rel_pk[(p0 >> 16) * D + lane];
      unsigned int rb = rel_pk[(p1 >> 16) * D + lane];
      unsigned int rc = rel_pk[(p2 >> 16) * D + lane];
      unsigned int rd = rel_pk[(p3 >> 16) * D + lane];
      float2 xf, rf;
      xf = unpack_h2(xa);  rf = unpack_h2(ra);
      a0 = fmaf(xf.x, rf.x, a0); a1 = fmaf(xf.y, rf.y, a1);
      xf = unpack_h2(xbv); rf = unpack_h2(rb);
      a0 = fmaf(xf.x, rf.x, a0); a1 = fmaf(xf.y, rf.y, a1);
      xf = unpack_h2(xc);  rf = unpack_h2(rc);
      a0 = fmaf(xf.x, rf.x, a0); a1 = fmaf(xf.y, rf.y, a1);
      xf = unpack_h2(xd);  rf = unpack_h2(rd);
      a0 = fmaf(xf.x, rf.x, a0); a1 = fmaf(xf.y, rf.y, a1);
    }
    for (; j < m; ++j) {
      unsigned int pk = __shfl(pkl, j);
      float2 xf = unpack_h2(xb[(size_t)(pk & 0xffffu) * D + lane]);
      float2 rf = unpack_h2(rel_pk[(pk >> 16) * D + lane]);
      a0 = fmaf(xf.x, rf.x, a0); a1 = fmaf(xf.y, rf.y, a1);
    }
    for (int jj = rs + 64; jj < re; ++jj) {      // deg>64 overflow (rare)
      unsigned int pk = es[jj];
      float2 xf = unpack_h2(xb[(size_t)(pk & 0xffffu) * D + lane]);
      float2 rf = unpack_h2(rel_pk[(pk >> 16) * D + lane]);
      a0 = fmaf(xf.x, rf.x, a0); a1 = fmaf(xf.y, rf.y, a1);
    }
  }
  if (n == h0) a0 += q2[lane].x;                 // + boundary (fp32)
  if (n == h1) a1 += q2[lane].y;
  xrow0[(size_t)n * 2 * D + D + lane] = (_Float16)a0;   // agg-half of A rows
  xrow1[(size_t)n * 2 * D + D + lane] = (_Float16)a1;
}

// ---- MFMA linear + LN + relu + shortcut ----
// One wave per 16-node tile, both batches. Zero LDS. Grid 2500 x 64.
// Residual read from xb (f16) — no fp32 x buffer.
__global__ __launch_bounds__(64) void k_linear(
    unsigned int* __restrict__ xb,
    _Float16* __restrict__ xrow0, _Float16* __restrict__ xrow1,
    const unsigned short* __restrict__ Wf,
    const float* __restrict__ lin_b, const float* __restrict__ ln_g,
    const float* __restrict__ ln_b, int layer) {
  int lane = threadIdx.x;
  int nb = blockIdx.x * 16;
  int c = lane & 15, rg = lane >> 4;
  // B-fragments (16 x 16 B, L2-hot)
  const v8h* wf = (const v8h*)(Wf + (size_t)layer * 8192);
  v8h Bf[4][4];
  #pragma unroll
  for (int ct = 0; ct < 4; ++ct)
    #pragma unroll
    for (int ks = 0; ks < 4; ++ks)
      Bf[ct][ks] = wf[(ct * 4 + ks) * 64 + lane];
  v4f acc0[4], acc1[4];
  #pragma unroll
  for (int ct = 0; ct < 4; ++ct) {
    acc0[ct] = (v4f){0.f, 0.f, 0.f, 0.f};
    acc1[ct] = (v4f){0.f, 0.f, 0.f, 0.f};
  }
  // K-loop: 4 k-steps x (2 A-loads + 8 MFMA)
  #pragma unroll
  for (int ks = 0; ks < 4; ++ks) {
    size_t aoff = (size_t)(nb + c) * 2 * D + ks * 32 + rg * 8;
    v8h A0 = *(const v8h*)(xrow0 + aoff);
    v8h A1 = *(const v8h*)(xrow1 + aoff);
    #pragma unroll
    for (int ct = 0; ct < 4; ++ct) {
      acc0[ct] = __builtin_amdgcn_mfma_f32_16x16x32_f16(A0, Bf[ct][ks], acc0[ct], 0, 0, 0);
      acc1[ct] = __builtin_amdgcn_mfma_f32_16x16x32_f16(A1, Bf[ct][ks], acc1[ct], 0, 0, 0);
    }
  }
  // epilogue: +bias, LN over 64 outs (16-lane col-group x 4 ct), relu, +x
  float bias4[4], g4[4], be4[4];
  #pragma unroll
  for (int ct = 0; ct < 4; ++ct) {
    int d = ct * 16 + c;
    bias4[ct] = lin_b[layer * D + d];
    g4[ct]    = ln_g[layer * D + d];
    be4[ct]   = ln_b[layer * D + d];
  }
  #pragma unroll
  for (int j = 0; j < 4; ++j) {
    int node = nb + rg * 4 + j;
    float v0[4], v1[4];
    float s10 = 0.f, s20 = 0.f, s11 = 0.f, s21 = 0.f;
    #pragma unroll
    for (int ct = 0; ct < 4; ++ct) {
      v0[ct] = acc0[ct][j] + bias4[ct];
      v1[ct] = acc1[ct][j] + bias4[ct];
      s10 += v0[ct]; s20 += v0[ct] * v0[ct];
      s11 += v1[ct]; s21 += v1[ct] * v1[ct];
    }
    #pragma unroll
    for (int mk = 1; mk < 16; mk <<= 1) {   // reduce over the 16-lane col group
      s10 += __shfl_xor(s10, mk); s20 += __shfl_xor(s20, mk);
      s11 += __shfl_xor(s11, mk); s21 += __shfl_xor(s21, mk);
    }
    float mu0 = s10 * (1.f / D), var0 = s20 * (1.f / D) - mu0 * mu0;
    float mu1 = s11 * (1.f / D), var1 = s21 * (1.f / D) - mu1 * mu1;
    float rs0 = rsqrtf(var0 + EPS), rs1 = rsqrtf(var1 + EPS);
    #pragma unroll
    for (int ct = 0; ct < 4; ++ct) {
      int d = ct * 16 + c;
      float o0 = fmaxf((v0[ct] - mu0) * rs0 * g4[ct] + be4[ct], 0.f);
      float o1 = fmaxf((v1[ct] - mu1) * rs1 * g4[ct] + be4[ct], 0.f);
      float2 xv = unpack_h2(xb[(size_t)node * D + d]);    // f16 residual
      float r0 = o0 + xv.x, r1 = o1 + xv.y;
      xb[(size_t)node * D + d] = pack_h2(r0, r1);          // for gather / residual
      xrow0[(size_t)node * 2 * D + d] = (_Float16)r0;      // x-half for next linear/mlp
      xrow1[(size_t)node * 2 * D + d] = (_Float16)r1;
    }
  }
}

// ---- MFMA final MLP: relu([x, query] @ mlp_w + mlp_b) -> fp32 out ----
__global__ __launch_bounds__(64) void k_mlp(
    const _Float16* __restrict__ xrow0, const _Float16* __restrict__ xrow1,
    const _Float16* __restrict__ qh,            // [2][64] f16
    const unsigned short* __restrict__ Wm,      // 32 fragments
    const float* __restrict__ mlp_b,
    float* __restrict__ outf) {
  int lane = threadIdx.x;
  int nb = blockIdx.x * 16;
  int c = lane & 15, rg = lane >> 4;
  const v8h* wm = (const v8h*)Wm;
  v4f acc0[8], acc1[8];
  #pragma unroll
  for (int ct = 0; ct < 8; ++ct) {
    acc0[ct] = (v4f){0.f, 0.f, 0.f, 0.f};
    acc1[ct] = (v4f){0.f, 0.f, 0.f, 0.f};
  }
  #pragma unroll
  for (int ks = 0; ks < 4; ++ks) {
    v8h A0, A1;
    if (ks < 2) {                       // x half: k = ks*32 + rg*8 + j in [0,64)
      size_t aoff = (size_t)(nb + c) * 2 * D + ks * 32 + rg * 8;
      A0 = *(const v8h*)(xrow0 + aoff);
      A1 = *(const v8h*)(xrow1 + aoff);
    } else {                            // query half: node-invariant
      int qoff = (ks - 2) * 32 + rg * 8;
      A0 = *(const v8h*)(qh + qoff);
      A1 = *(const v8h*)(qh + D + qoff);
    }
    #pragma unroll
    for (int ct = 0; ct < 8; ++ct) {
      v8h Bv = wm[(ct * 4 + ks) * 64 + lane];
      acc0[ct] = __builtin_amdgcn_mfma_f32_16x16x32_f16(A0, Bv, acc0[ct], 0, 0, 0);
      acc1[ct] = __builtin_amdgcn_mfma_f32_16x16x32_f16(A1, Bv, acc1[ct], 0, 0, 0);
    }
  }
  // epilogue: +bias, relu, store. out flat = [2][N][128] fp32.
  #pragma unroll
  for (int ct = 0; ct < 8; ++ct) {
    int d = ct * 16 + c;
    float bias = mlp_b[d];
    #pragma unroll
    for (int j = 0; j < 4; ++j) {
      int node = nb + rg * 4 + j;
      outf[(size_t)node * 2 * D + d]       = fmaxf(acc0[ct][j] + bias, 0.f);
      outf[((size_t)N + node) * 2 * D + d] = fmaxf(acc1[ct][j] + bias, 0.f);
    }
  }
}

}  // namespace

extern "C" void kernel_launch(void* const* d_in, const int* in_sizes, int n_in,
                              void* d_out, int out_size, void* d_ws, size_t ws_size,
                              hipStream_t stream) {
  const float* rel_reps = (const float*)d_in[0];
  const int* h_index    = (const int*)d_in[1];
  const int* r_index    = (const int*)d_in[2];
  const int* edge_index = (const int*)d_in[3];
  const int* edge_type  = (const int*)d_in[4];
  const float* proj_w1  = (const float*)d_in[5];
  const float* proj_b1  = (const float*)d_in[6];
  const float* proj_w2  = (const float*)d_in[7];
  const float* proj_b2  = (const float*)d_in[8];
  const float* lin_w    = (const float*)d_in[9];
  const float* lin_b    = (const float*)d_in[10];
  const float* ln_g     = (const float*)d_in[11];
  const float* ln_b     = (const float*)d_in[12];
  const float* mlp_w    = (const float*)d_in[13];
  const float* mlp_b    = (const float*)d_in[14];

  // workspace: rel_all | query | cnt | row_ptr | cursor | es | bsum |
  //            xb | rel_pk | Wf | xrow0 | xrow1 | Wm | qh
  float* rel_all = (float*)d_ws;                       // L*R*D float2
  float* query   = rel_all + (size_t)2 * L * R * D;    // D float2
  int*   cnt     = (int*)(query + 2 * D);
  int*   row_ptr = cnt + N;
  int*   cursor  = row_ptr + (N + 1);
  unsigned int* es  = (unsigned int*)(cursor + N);
  int*   bsum    = (int*)(es + E);
  unsigned int* xb = (unsigned int*)(bsum + NB);       // N*D packed f16x2
  unsigned int* rel_pk = xb + (size_t)N * D;           // L*R*D packed
  unsigned short* Wf = (unsigned short*)(rel_pk + (size_t)L * R * D);  // L*8192
  _Float16* xrow0 = (_Float16*)(Wf + (size_t)L * 8192);  // N*128
  _Float16* xrow1 = xrow0 + (size_t)N * 2 * D;           // N*128
  unsigned short* Wm = (unsigned short*)(xrow1 + (size_t)N * 2 * D);  // 16384
  _Float16* qh = (_Float16*)(Wm + 16384);                // 128

  const int* srcp = edge_index;
  const int* dstp = edge_index + E;

  hipMemsetAsync(xb, 0, (size_t)N * D * sizeof(unsigned int), stream);
  hipMemsetAsync(xrow0, 0, (size_t)N * 2 * D * sizeof(_Float16) * 2, stream);  // both rows
  hipMemsetAsync(cnt, 0, N * sizeof(int), stream);
  k_init<<<1, 64, 0, stream>>>(rel_reps, h_index, r_index,
                               xb, xrow0, xrow1, query, qh);
  k_rel<<<L * B * R, 64, 0, stream>>>(rel_reps, proj_w1, proj_b1, proj_w2, proj_b2, rel_all);
  k_pack_rel<<<(L * R * D + 255) / 256, 256, 0, stream>>>((const float2*)rel_all, rel_pk);
  k_pack_w<<<L * 16, 64, 0, stream>>>(lin_w, Wf);
  k_pack_wm<<<32, 64, 0, stream>>>(mlp_w, Wm);
  k_hist<<<EB, 256, 0, stream>>>(dstp, cnt);
  k_scan1<<<NB, 256, 0, stream>>>(cnt, row_ptr, bsum);
  k_scan2<<<1, 256, 0, stream>>>(bsum, row_ptr);
  k_scan3<<<NB, 256, 0, stream>>>(row_ptr, bsum, cursor);
  k_fill<<<EB, 256, 0, stream>>>(srcp, dstp, edge_type, cursor, es);

  for (int l = 0; l < L; ++l) {
    k_gather<<<N / 4, 256, 0, stream>>>(xb, xrow0, xrow1,
                                        rel_pk + (size_t)l * R * D,
                                        row_ptr, es, (const float2*)query, h_index,
                                        (l == 0) ? 1 : 0);
    k_linear<<<N / 16, 64, 0, stream>>>(xb, xrow0, xrow1,
                                        Wf, lin_b, ln_g, ln_b, l);
  }
  k_mlp<<<N / 16, 64, 0, stream>>>(xrow0, xrow1, qh, Wm, mlp_b, (float*)d_out);
}

// Round 12
// 376.283 us; speedup vs baseline: 1.7948x; 1.0457x over previous
//
#include <hip/hip_runtime.h>
#include <hip/hip_bf16.h>

namespace {

constexpr int B = 2;
constexpr int N = 40000;
constexpr int E = 400000;
constexpr int R = 64;
constexpr int D = 64;
constexpr int L = 6;
constexpr float EPS = 1e-5f;
constexpr int NB = (N + 255) / 256;   // 157 node-grid blocks
constexpr int EB = (E + 255) / 256;   // 1563 edge-grid blocks

typedef _Float16 v8h __attribute__((ext_vector_type(8)));
typedef _Float16 v2h __attribute__((ext_vector_type(2)));
typedef float    v4f __attribute__((ext_vector_type(4)));

__device__ __forceinline__ unsigned int pack_h2(float a, float b) {
  v2h p; p.x = (_Float16)a; p.y = (_Float16)b;
  return __builtin_bit_cast(unsigned int, p);
}
__device__ __forceinline__ float2 unpack_h2(unsigned int u) {
  v2h p = __builtin_bit_cast(v2h, u);
  return make_float2((float)p.x, (float)p.y);
}

// Batch-interleaved packed element = (batch0, batch1) f16 in one dword.

// ---- init: query gather + boundary scatter (xb, xrow pre-zeroed) ----
__global__ void k_init(const float* __restrict__ rel_reps,
                       const int* __restrict__ h_index, const int* __restrict__ r_index,
                       unsigned int* __restrict__ xb,
                       _Float16* __restrict__ xrow0, _Float16* __restrict__ xrow1,
                       float* __restrict__ query_f, _Float16* __restrict__ qh) {
  int d = threadIdx.x;               // 64 threads
  int h0 = h_index[0], h1 = h_index[1];
  float q0 = rel_reps[r_index[0] * D + d];
  float q1 = rel_reps[(R + r_index[1]) * D + d];
  query_f[d * 2] = q0; query_f[d * 2 + 1] = q1;
  qh[d]     = (_Float16)q0;          // f16 query, per batch (for k_mlp A-frags)
  qh[D + d] = (_Float16)q1;
  if (h0 == h1) {
    xb[(size_t)h0 * D + d] = pack_h2(q0, q1);
  } else {
    xb[(size_t)h0 * D + d] = pack_h2(q0, 0.f);
    xb[(size_t)h1 * D + d] = pack_h2(0.f, q1);
  }
  xrow0[(size_t)h0 * 2 * D + d] = (_Float16)q0;   // x-half of A rows
  xrow1[(size_t)h1 * 2 * D + d] = (_Float16)q1;
}

// ---- relation projection MLP for all layers: rel_f[l][r*64+d] = (b0, b1) fp32 ----
__global__ __launch_bounds__(64) void k_rel(
    const float* __restrict__ rel_reps,
    const float* __restrict__ pw1, const float* __restrict__ pb1,
    const float* __restrict__ pw2, const float* __restrict__ pb2,
    float* __restrict__ rel_f) {
  __shared__ float row[D];
  __shared__ float row2[D];
  int idx = blockIdx.x;             // [0, L*B*R)
  int l = idx / (B * R);
  int br = idx - l * (B * R);       // b*R + r
  int b = br / R, r = br - b * R;
  int d = threadIdx.x;
  row[d] = rel_reps[(size_t)br * D + d];
  __syncthreads();
  const float* w1 = pw1 + (size_t)l * D * D;
  float acc = pb1[l * D + d];
  for (int k = 0; k < D; ++k) acc = fmaf(row[k], w1[k * D + d], acc);
  row2[d] = fmaxf(acc, 0.f);
  __syncthreads();
  const float* w2 = pw2 + (size_t)l * D * D;
  float acc2 = pb2[l * D + d];
  for (int k = 0; k < D; ++k) acc2 = fmaf(row2[k], w2[k * D + d], acc2);
  rel_f[(((size_t)l * R + r) * D + d) * 2 + b] = acc2;
}

// pack rel fp32-float2 -> f16x2 dword (L*R*D entries)
__global__ __launch_bounds__(256) void k_pack_rel(const float2* __restrict__ rel2,
                                                  unsigned int* __restrict__ rel_pk) {
  int i = blockIdx.x * 256 + threadIdx.x;
  if (i < L * R * D) {
    float2 v = rel2[i];
    rel_pk[i] = pack_h2(v.x, v.y);
  }
}

// pack lin_w fp32 -> f16 MFMA B-fragments, fragment-contiguous.
__global__ __launch_bounds__(64) void k_pack_w(const float* __restrict__ lin_w,
                                               unsigned short* __restrict__ Wf) {
  int idx = blockIdx.x;             // [0, L*16)
  int l = idx >> 4;
  int ct = (idx >> 2) & 3, ks = idx & 3;
  int lane = threadIdx.x;
  int n = ct * 16 + (lane & 15);
  #pragma unroll
  for (int j = 0; j < 8; ++j) {
    int k = ks * 32 + (lane >> 4) * 8 + j;
    _Float16 v = (_Float16)lin_w[(size_t)l * 2 * D * D + (size_t)k * D + n];
    Wf[(size_t)l * 8192 + ((size_t)(ct * 4 + ks) * 64 + lane) * 8 + j] =
        __builtin_bit_cast(unsigned short, v);
  }
}

// pack mlp_w fp32 [128][128] -> f16 MFMA B-fragments (8 ct x 4 ks).
__global__ __launch_bounds__(64) void k_pack_wm(const float* __restrict__ mlp_w,
                                                unsigned short* __restrict__ Wm) {
  int idx = blockIdx.x;             // [0, 32): ct = idx>>2, ks = idx&3
  int ct = idx >> 2, ks = idx & 3;
  int lane = threadIdx.x;
  int n = ct * 16 + (lane & 15);
  #pragma unroll
  for (int j = 0; j < 8; ++j) {
    int k = ks * 32 + (lane >> 4) * 8 + j;
    _Float16 v = (_Float16)mlp_w[(size_t)k * 2 * D + n];
    Wm[((size_t)idx * 64 + lane) * 8 + j] = __builtin_bit_cast(unsigned short, v);
  }
}

// ---- CSR build ----
__global__ __launch_bounds__(256) void k_hist(const int* __restrict__ dst,
                                              int* __restrict__ cnt) {
  int e = blockIdx.x * 256 + threadIdx.x;
  if (e < E) atomicAdd(&cnt[dst[e]], 1);
}

__global__ __launch_bounds__(256) void k_scan1(const int* __restrict__ cnt,
                                               int* __restrict__ row_ptr,
                                               int* __restrict__ bsum) {
  __shared__ int s[256];
  int t = threadIdx.x;
  int i = blockIdx.x * 256 + t;
  int v = (i < N) ? cnt[i] : 0;
  s[t] = v;
  __syncthreads();
  #pragma unroll
  for (int off = 1; off < 256; off <<= 1) {   // Hillis-Steele inclusive
    int u = (t >= off) ? s[t - off] : 0;
    __syncthreads();
    s[t] += u;
    __syncthreads();
  }
  if (i < N) row_ptr[i] = s[t] - v;           // exclusive-in-block
  if (t == 255) bsum[blockIdx.x] = s[255];
}

__global__ __launch_bounds__(256) void k_scan2(int* __restrict__ bsum,
                                               int* __restrict__ row_ptr) {
  __shared__ int s[NB];
  int t = threadIdx.x;
  if (t < NB) s[t] = bsum[t];
  __syncthreads();
  if (t == 0) {
    int run = 0;
    for (int i = 0; i < NB; ++i) { int v = s[i]; s[i] = run; run += v; }
    row_ptr[N] = run;                         // = E
  }
  __syncthreads();
  if (t < NB) bsum[t] = s[t];
}

__global__ __launch_bounds__(256) void k_scan3(int* __restrict__ row_ptr,
                                               const int* __restrict__ bsum,
                                               int* __restrict__ cursor) {
  int i = blockIdx.x * 256 + threadIdx.x;
  if (i < N) {
    int v = row_ptr[i] + bsum[blockIdx.x];
    row_ptr[i] = v;
    cursor[i] = v;
  }
}

__global__ __launch_bounds__(256) void k_fill(const int* __restrict__ src,
                                              const int* __restrict__ dst,
                                              const int* __restrict__ etype,
                                              int* __restrict__ cursor,
                                              unsigned int* __restrict__ es) {
  int e = blockIdx.x * 256 + threadIdx.x;
  if (e < E) {
    int p = atomicAdd(&cursor[dst[e]], 1);
    es[p] = (unsigned int)src[e] | ((unsigned int)etype[e] << 16);  // src < 65536
  }
}

// ---- gather: TWO nodes per wave (half-wave each, uint2 8B loads/lane).
// Predicated unroll-4 main loop (no serial remainder); deg<=32 fast path,
// overflow loop for deg>32 (P~0 at mean deg 10). Zero LDS, 32 waves/CU.
// Writes agg-half of xrow (f16).
__global__ __launch_bounds__(256, 8) void k_gather(
    const unsigned int* __restrict__ xb,
    _Float16* __restrict__ xrow0, _Float16* __restrict__ xrow1,
    const unsigned int* __restrict__ rel_pk,     // [R*D] this layer, packed
    const int* __restrict__ row_ptr, const unsigned int* __restrict__ es,
    const float2* __restrict__ q2, const int* __restrict__ h_index, int first) {
  int tid = threadIdx.x;
  int lane = tid & 63;
  int h = lane >> 5;                 // half: 0 or 1
  int ln = lane & 31;                // lane within half (dims 2ln, 2ln+1)
  int w = (blockIdx.x * 256 + tid) >> 6;       // wave id in [0, N/2)
  int n = w * 2 + h;                 // node for this half
  int h0 = h_index[0], h1 = h_index[1];
  int rp = 0;
  if (lane < 3) rp = row_ptr[2 * w + lane];    // row_ptr[2w .. 2w+2]
  int rs = __shfl(rp, h);
  int re = __shfl(rp, h + 1);
  int deg = re - rs;
  int dc = min(deg, 32);
  unsigned int esv = 0;
  if (ln < dc) esv = es[rs + ln];              // half's edge list, one load
  float a0x = 0.f, a0y = 0.f, a1x = 0.f, a1y = 0.f;
  if (first) {
    // layer 0: x nonzero only at h0 (.x) / h1 (.y); loads only on match
    for (int j = 0; j < dc; ++j) {
      unsigned int pk = __shfl(esv, (h << 5) | j);
      int s = (int)(pk & 0xffffu), et = (int)(pk >> 16);
      if (s == h0 || s == h1) {
        uint2 xv = *(const uint2*)&xb[(size_t)s * D + 2 * ln];
        uint2 rv = *(const uint2*)&rel_pk[et * D + 2 * ln];
        float2 xfx = unpack_h2(xv.x), xfy = unpack_h2(xv.y);
        float2 rfx = unpack_h2(rv.x), rfy = unpack_h2(rv.y);
        if (s == h0) { a0x = fmaf(xfx.x, rfx.x, a0x); a0y = fmaf(xfy.x, rfy.x, a0y); }
        if (s == h1) { a1x = fmaf(xfx.y, rfx.y, a1x); a1y = fmaf(xfy.y, rfy.y, a1y); }
      }
    }
    for (int j = rs + 32; j < re; ++j) {       // overflow (rare)
      unsigned int pk = es[j];
      int s = (int)(pk & 0xffffu), et = (int)(pk >> 16);
      if (s == h0 || s == h1) {
        uint2 xv = *(const uint2*)&xb[(size_t)s * D + 2 * ln];
        uint2 rv = *(const uint2*)&rel_pk[et * D + 2 * ln];
        float2 xfx = unpack_h2(xv.x), xfy = unpack_h2(xv.y);
        float2 rfx = unpack_h2(rv.x), rfy = unpack_h2(rv.y);
        if (s == h0) { a0x = fmaf(xfx.x, rfx.x, a0x); a0y = fmaf(xfy.x, rfy.x, a0y); }
        if (s == h1) { a1x = fmaf(xfx.y, rfx.y, a1x); a1y = fmaf(xfy.y, rfy.y, a1y); }
      }
    }
  } else {
    int rounds = (dc + 3) >> 2;
    int maxr = max(__shfl(rounds, 0), __shfl(rounds, 32));   // wave-uniform bound
    for (int jr = 0; jr < maxr; ++jr) {
      int j = jr * 4;
      // clamped edge indices (safe when this half is already done or dc==0)
      int i0 = max(min(j + 0, dc - 1), 0), i1 = max(min(j + 1, dc - 1), 0);
      int i2 = max(min(j + 2, dc - 1), 0), i3 = max(min(j + 3, dc - 1), 0);
      unsigned int p0 = __shfl(esv, (h << 5) | i0);
      unsigned int p1 = __shfl(esv, (h << 5) | i1);
      unsigned int p2 = __shfl(esv, (h << 5) | i2);
      unsigned int p3 = __shfl(esv, (h << 5) | i3);
      uint2 xv0 = *(const uint2*)&xb[(size_t)(p0 & 0xffffu) * D + 2 * ln];
      uint2 xv1 = *(const uint2*)&xb[(size_t)(p1 & 0xffffu) * D + 2 * ln];
      uint2 xv2 = *(const uint2*)&xb[(size_t)(p2 & 0xffffu) * D + 2 * ln];
      uint2 xv3 = *(const uint2*)&xb[(size_t)(p3 & 0xffffu) * D + 2 * ln];
      uint2 rv0 = *(const uint2*)&rel_pk[(p0 >> 16) * D + 2 * ln];
      uint2 rv1 = *(const uint2*)&rel_pk[(p1 >> 16) * D + 2 * ln];
      uint2 rv2 = *(const uint2*)&rel_pk[(p2 >> 16) * D + 2 * ln];
      uint2 rv3 = *(const uint2*)&rel_pk[(p3 >> 16) * D + 2 * ln];
      if (j + 0 < dc) {
        float2 xfx = unpack_h2(xv0.x), xfy = unpack_h2(xv0.y);
        float2 rfx = unpack_h2(rv0.x), rfy = unpack_h2(rv0.y);
        a0x = fmaf(xfx.x, rfx.x, a0x); a1x = fmaf(xfx.y, rfx.y, a1x);
        a0y = fmaf(xfy.x, rfy.x, a0y); a1y = fmaf(xfy.y, rfy.y, a1y);
      }
      if (j + 1 < dc) {
        float2 xfx = unpack_h2(xv1.x), xfy = unpack_h2(xv1.y);
        float2 rfx = unpack_h2(rv1.x), rfy = unpack_h2(rv1.y);
        a0x = fmaf(xfx.x, rfx.x, a0x); a1x = fmaf(xfx.y, rfx.y, a1x);
        a0y = fmaf(xfy.x, rfy.x, a0y); a1y = fmaf(xfy.y, rfy.y, a1y);
      }
      if (j + 2 < dc) {
        float2 xfx = unpack_h2(xv2.x), xfy = unpack_h2(xv2.y);
        float2 rfx = unpack_h2(rv2.x), rfy = unpack_h2(rv2.y);
        a0x = fmaf(xfx.x, rfx.x, a0x); a1x = fmaf(xfx.y, rfx.y, a1x);
        a0y = fmaf(xfy.x, rfy.x, a0y); a1y = fmaf(xfy.y, rfy.y, a1y);
      }
      if (j + 3 < dc) {
        float2 xfx = unpack_h2(xv3.x), xfy = unpack_h2(xv3.y);
        float2 rfx = unpack_h2(rv3.x), rfy = unpack_h2(rv3.y);
        a0x = fmaf(xfx.x, rfx.x, a0x); a1x = fmaf(xfx.y, rfx.y, a1x);
        a0y = fmaf(xfy.x, rfy.x, a0y); a1y = fmaf(xfy.y, rfy.y, a1y);
      }
    }
    for (int j = rs + 32; j < re; ++j) {       // overflow (rare)
      unsigned int pk = es[j];
      uint2 xv = *(const uint2*)&xb[(size_t)(pk & 0xffffu) * D + 2 * ln];
      uint2 rv = *(const uint2*)&rel_pk[(pk >> 16) * D + 2 * ln];
      float2 xfx = unpack_h2(xv.x), xfy = unpack_h2(xv.y);
      float2 rfx = unpack_h2(rv.x), rfy = unpack_h2(rv.y);
      a0x = fmaf(xfx.x, rfx.x, a0x); a1x = fmaf(xfx.y, rfx.y, a1x);
      a0y = fmaf(xfy.x, rfy.x, a0y); a1y = fmaf(xfy.y, rfy.y, a1y);
    }
  }
  if (n == h0) {                     // + boundary (fp32)
    float4 qq = *(const float4*)&q2[2 * ln];   // (q[2ln].b0, q[2ln].b1, q[2ln+1].b0, q[2ln+1].b1)
    a0x += qq.x; a0y += qq.z;
  }
  if (n == h1) {
    float4 qq = *(const float4*)&q2[2 * ln];
    a1x += qq.y; a1y += qq.w;
  }
  v2h s0; s0.x = (_Float16)a0x; s0.y = (_Float16)a0y;
  v2h s1; s1.x = (_Float16)a1x; s1.y = (_Float16)a1y;
  *(v2h*)&xrow0[(size_t)n * 2 * D + D + 2 * ln] = s0;   // agg-half of A rows
  *(v2h*)&xrow1[(size_t)n * 2 * D + D + 2 * ln] = s1;
}

// ---- MFMA linear + LN + relu + shortcut ----
// One wave per 16-node tile, both batches. Zero LDS. Grid 2500 x 64.
// Residual read from xb (f16) — no fp32 x buffer.
__global__ __launch_bounds__(64) void k_linear(
    unsigned int* __restrict__ xb,
    _Float16* __restrict__ xrow0, _Float16* __restrict__ xrow1,
    const unsigned short* __restrict__ Wf,
    const float* __restrict__ lin_b, const float* __restrict__ ln_g,
    const float* __restrict__ ln_b, int layer) {
  int lane = threadIdx.x;
  int nb = blockIdx.x * 16;
  int c = lane & 15, rg = lane >> 4;
  // B-fragments (16 x 16 B, L2-hot)
  const v8h* wf = (const v8h*)(Wf + (size_t)layer * 8192);
  v8h Bf[4][4];
  #pragma unroll
  for (int ct = 0; ct < 4; ++ct)
    #pragma unroll
    for (int ks = 0; ks < 4; ++ks)
      Bf[ct][ks] = wf[(ct * 4 + ks) * 64 + lane];
  v4f acc0[4], acc1[4];
  #pragma unroll
  for (int ct = 0; ct < 4; ++ct) {
    acc0[ct] = (v4f){0.f, 0.f, 0.f, 0.f};
    acc1[ct] = (v4f){0.f, 0.f, 0.f, 0.f};
  }
  // K-loop: 4 k-steps x (2 A-loads + 8 MFMA)
  #pragma unroll
  for (int ks = 0; ks < 4; ++ks) {
    size_t aoff = (size_t)(nb + c) * 2 * D + ks * 32 + rg * 8;
    v8h A0 = *(const v8h*)(xrow0 + aoff);
    v8h A1 = *(const v8h*)(xrow1 + aoff);
    #pragma unroll
    for (int ct = 0; ct < 4; ++ct) {
      acc0[ct] = __builtin_amdgcn_mfma_f32_16x16x32_f16(A0, Bf[ct][ks], acc0[ct], 0, 0, 0);
      acc1[ct] = __builtin_amdgcn_mfma_f32_16x16x32_f16(A1, Bf[ct][ks], acc1[ct], 0, 0, 0);
    }
  }
  // epilogue: +bias, LN over 64 outs (16-lane col-group x 4 ct), relu, +x
  float bias4[4], g4[4], be4[4];
  #pragma unroll
  for (int ct = 0; ct < 4; ++ct) {
    int d = ct * 16 + c;
    bias4[ct] = lin_b[layer * D + d];
    g4[ct]    = ln_g[layer * D + d];
    be4[ct]   = ln_b[layer * D + d];
  }
  #pragma unroll
  for (int j = 0; j < 4; ++j) {
    int node = nb + rg * 4 + j;
    float v0[4], v1[4];
    float s10 = 0.f, s20 = 0.f, s11 = 0.f, s21 = 0.f;
    #pragma unroll
    for (int ct = 0; ct < 4; ++ct) {
      v0[ct] = acc0[ct][j] + bias4[ct];
      v1[ct] = acc1[ct][j] + bias4[ct];
      s10 += v0[ct]; s20 += v0[ct] * v0[ct];
      s11 += v1[ct]; s21 += v1[ct] * v1[ct];
    }
    #pragma unroll
    for (int mk = 1; mk < 16; mk <<= 1) {   // reduce over the 16-lane col group
      s10 += __shfl_xor(s10, mk); s20 += __shfl_xor(s20, mk);
      s11 += __shfl_xor(s11, mk); s21 += __shfl_xor(s21, mk);
    }
    float mu0 = s10 * (1.f / D), var0 = s20 * (1.f / D) - mu0 * mu0;
    float mu1 = s11 * (1.f / D), var1 = s21 * (1.f / D) - mu1 * mu1;
    float rs0 = rsqrtf(var0 + EPS), rs1 = rsqrtf(var1 + EPS);
    #pragma unroll
    for (int ct = 0; ct < 4; ++ct) {
      int d = ct * 16 + c;
      float o0 = fmaxf((v0[ct] - mu0) * rs0 * g4[ct] + be4[ct], 0.f);
      float o1 = fmaxf((v1[ct] - mu1) * rs1 * g4[ct] + be4[ct], 0.f);
      float2 xv = unpack_h2(xb[(size_t)node * D + d]);    // f16 residual
      float r0 = o0 + xv.x, r1 = o1 + xv.y;
      xb[(size_t)node * D + d] = pack_h2(r0, r1);          // for gather / residual
      xrow0[(size_t)node * 2 * D + d] = (_Float16)r0;      // x-half for next linear/mlp
      xrow1[(size_t)node * 2 * D + d] = (_Float16)r1;
    }
  }
}

// ---- MFMA final MLP: relu([x, query] @ mlp_w + mlp_b) -> fp32 out ----
__global__ __launch_bounds__(64) void k_mlp(
    const _Float16* __restrict__ xrow0, const _Float16* __restrict__ xrow1,
    const _Float16* __restrict__ qh,            // [2][64] f16
    const unsigned short* __restrict__ Wm,      // 32 fragments
    const float* __restrict__ mlp_b,
    float* __restrict__ outf) {
  int lane = threadIdx.x;
  int nb = blockIdx.x * 16;
  int c = lane & 15, rg = lane >> 4;
  const v8h* wm = (const v8h*)Wm;
  v4f acc0[8], acc1[8];
  #pragma unroll
  for (int ct = 0; ct < 8; ++ct) {
    acc0[ct] = (v4f){0.f, 0.f, 0.f, 0.f};
    acc1[ct] = (v4f){0.f, 0.f, 0.f, 0.f};
  }
  #pragma unroll
  for (int ks = 0; ks < 4; ++ks) {
    v8h A0, A1;
    if (ks < 2) {                       // x half: k = ks*32 + rg*8 + j in [0,64)
      size_t aoff = (size_t)(nb + c) * 2 * D + ks * 32 + rg * 8;
      A0 = *(const v8h*)(xrow0 + aoff);
      A1 = *(const v8h*)(xrow1 + aoff);
    } else {                            // query half: node-invariant
      int qoff = (ks - 2) * 32 + rg * 8;
      A0 = *(const v8h*)(qh + qoff);
      A1 = *(const v8h*)(qh + D + qoff);
    }
    #pragma unroll
    for (int ct = 0; ct < 8; ++ct) {
      v8h Bv = wm[(ct * 4 + ks) * 64 + lane];
      acc0[ct] = __builtin_amdgcn_mfma_f32_16x16x32_f16(A0, Bv, acc0[ct], 0, 0, 0);
      acc1[ct] = __builtin_amdgcn_mfma_f32_16x16x32_f16(A1, Bv, acc1[ct], 0, 0, 0);
    }
  }
  // epilogue: +bias, relu, store. out flat = [2][N][128] fp32.
  #pragma unroll
  for (int ct = 0; ct < 8; ++ct) {
    int d = ct * 16 + c;
    float bias = mlp_b[d];
    #pragma unroll
    for (int j = 0; j < 4; ++j) {
      int node = nb + rg * 4 + j;
      outf[(size_t)node * 2 * D + d]       = fmaxf(acc0[ct][j] + bias, 0.f);
      outf[((size_t)N + node) * 2 * D + d] = fmaxf(acc1[ct][j] + bias, 0.f);
    }
  }
}

}  // namespace

extern "C" void kernel_launch(void* const* d_in, const int* in_sizes, int n_in,
                              void* d_out, int out_size, void* d_ws, size_t ws_size,
                              hipStream_t stream) {
  const float* rel_reps = (const float*)d_in[0];
  const int* h_index    = (const int*)d_in[1];
  const int* r_index    = (const int*)d_in[2];
  const int* edge_index = (const int*)d_in[3];
  const int* edge_type  = (const int*)d_in[4];
  const float* proj_w1  = (const float*)d_in[5];
  const float* proj_b1  = (const float*)d_in[6];
  const float* proj_w2  = (const float*)d_in[7];
  const float* proj_b2  = (const float*)d_in[8];
  const float* lin_w    = (const float*)d_in[9];
  const float* lin_b    = (const float*)d_in[10];
  const float* ln_g     = (const float*)d_in[11];
  const float* ln_b     = (const float*)d_in[12];
  const float* mlp_w    = (const float*)d_in[13];
  const float* mlp_b    = (const float*)d_in[14];

  // workspace: rel_all | query | cnt | row_ptr | cursor | es | bsum |
  //            xb | rel_pk | Wf | xrow0 | xrow1 | Wm | qh
  float* rel_all = (float*)d_ws;                       // L*R*D float2
  float* query   = rel_all + (size_t)2 * L * R * D;    // D float2
  int*   cnt     = (int*)(query + 2 * D);
  int*   row_ptr = cnt + N;
  int*   cursor  = row_ptr + (N + 1);
  unsigned int* es  = (unsigned int*)(cursor + N);
  int*   bsum    = (int*)(es + E);
  unsigned int* xb = (unsigned int*)(bsum + NB);       // N*D packed f16x2
  unsigned int* rel_pk = xb + (size_t)N * D;           // L*R*D packed
  unsigned short* Wf = (unsigned short*)(rel_pk + (size_t)L * R * D);  // L*8192
  _Float16* xrow0 = (_Float16*)(Wf + (size_t)L * 8192);  // N*128
  _Float16* xrow1 = xrow0 + (size_t)N * 2 * D;           // N*128
  unsigned short* Wm = (unsigned short*)(xrow1 + (size_t)N * 2 * D);  // 16384
  _Float16* qh = (_Float16*)(Wm + 16384);                // 128

  const int* srcp = edge_index;
  const int* dstp = edge_index + E;

  hipMemsetAsync(xb, 0, (size_t)N * D * sizeof(unsigned int), stream);
  hipMemsetAsync(xrow0, 0, (size_t)N * 2 * D * sizeof(_Float16) * 2, stream);  // both rows
  hipMemsetAsync(cnt, 0, N * sizeof(int), stream);
  k_init<<<1, 64, 0, stream>>>(rel_reps, h_index, r_index,
                               xb, xrow0, xrow1, query, qh);
  k_rel<<<L * B * R, 64, 0, stream>>>(rel_reps, proj_w1, proj_b1, proj_w2, proj_b2, rel_all);
  k_pack_rel<<<(L * R * D + 255) / 256, 256, 0, stream>>>((const float2*)rel_all, rel_pk);
  k_pack_w<<<L * 16, 64, 0, stream>>>(lin_w, Wf);
  k_pack_wm<<<32, 64, 0, stream>>>(mlp_w, Wm);
  k_hist<<<EB, 256, 0, stream>>>(dstp, cnt);
  k_scan1<<<NB, 256, 0, stream>>>(cnt, row_ptr, bsum);
  k_scan2<<<1, 256, 0, stream>>>(bsum, row_ptr);
  k_scan3<<<NB, 256, 0, stream>>>(row_ptr, bsum, cursor);
  k_fill<<<EB, 256, 0, stream>>>(srcp, dstp, edge_type, cursor, es);

  for (int l = 0; l < L; ++l) {
    k_gather<<<N / 8, 256, 0, stream>>>(xb, xrow0, xrow1,
                                        rel_pk + (size_t)l * R * D,
                                        row_ptr, es, (const float2*)query, h_index,
                                        (l == 0) ? 1 : 0);
    k_linear<<<N / 16, 64, 0, stream>>>(xb, xrow0, xrow1,
                                        Wf, lin_b, ln_g, ln_b, l);
  }
  k_mlp<<<N / 16, 64, 0, stream>>>(xrow0, xrow1, qh, Wm, mlp_b, (float*)d_out);
}

// Round 13
// 347.026 us; speedup vs baseline: 1.9461x; 1.0843x over previous
//
#include <hip/hip_runtime.h>
#include <hip/hip_bf16.h>

namespace {

constexpr int B = 2;
constexpr int N = 40000;
constexpr int E = 400000;
constexpr int R = 64;
constexpr int D = 64;
constexpr int L = 6;
constexpr float EPS = 1e-5f;
constexpr int NB = (N + 255) / 256;   // 157 node-grid blocks
constexpr int EB = (E + 255) / 256;   // 1563 edge-grid blocks

typedef _Float16 v8h __attribute__((ext_vector_type(8)));
typedef _Float16 v2h __attribute__((ext_vector_type(2)));
typedef float    v4f __attribute__((ext_vector_type(4)));

__device__ __forceinline__ unsigned int pack_h2(float a, float b) {
  v2h p; p.x = (_Float16)a; p.y = (_Float16)b;
  return __builtin_bit_cast(unsigned int, p);
}
__device__ __forceinline__ float2 unpack_h2(unsigned int u) {
  v2h p = __builtin_bit_cast(v2h, u);
  return make_float2((float)p.x, (float)p.y);
}

// Batch-interleaved packed element = (batch0, batch1) f16 in one dword.

// ---- relation projection MLP for all layers (+ last block does init) ----
__global__ __launch_bounds__(64) void k_rel(
    const float* __restrict__ rel_reps,
    const float* __restrict__ pw1, const float* __restrict__ pb1,
    const float* __restrict__ pw2, const float* __restrict__ pb2,
    float* __restrict__ rel_f,
    const int* __restrict__ h_index, const int* __restrict__ r_index,
    unsigned int* __restrict__ xb,
    _Float16* __restrict__ xrow0, _Float16* __restrict__ xrow1,
    float* __restrict__ query_f, _Float16* __restrict__ qh) {
  __shared__ float row[D];
  __shared__ float row2[D];
  int idx = blockIdx.x;             // [0, L*B*R] — last block = init
  int d = threadIdx.x;
  if (idx == L * B * R) {           // ---- init block ----
    int h0 = h_index[0], h1 = h_index[1];
    float q0 = rel_reps[r_index[0] * D + d];
    float q1 = rel_reps[(R + r_index[1]) * D + d];
    query_f[d * 2] = q0; query_f[d * 2 + 1] = q1;
    qh[d]     = (_Float16)q0;
    qh[D + d] = (_Float16)q1;
    if (h0 == h1) {
      xb[(size_t)h0 * D + d] = pack_h2(q0, q1);
    } else {
      xb[(size_t)h0 * D + d] = pack_h2(q0, 0.f);
      xb[(size_t)h1 * D + d] = pack_h2(0.f, q1);
    }
    xrow0[(size_t)h0 * 2 * D + d] = (_Float16)q0;   // x-half of A rows
    xrow1[(size_t)h1 * 2 * D + d] = (_Float16)q1;
    return;
  }
  int l = idx / (B * R);
  int br = idx - l * (B * R);       // b*R + r
  int b = br / R, r = br - b * R;
  row[d] = rel_reps[(size_t)br * D + d];
  __syncthreads();
  const float* w1 = pw1 + (size_t)l * D * D;
  float acc = pb1[l * D + d];
  for (int k = 0; k < D; ++k) acc = fmaf(row[k], w1[k * D + d], acc);
  row2[d] = fmaxf(acc, 0.f);
  __syncthreads();
  const float* w2 = pw2 + (size_t)l * D * D;
  float acc2 = pb2[l * D + d];
  for (int k = 0; k < D; ++k) acc2 = fmaf(row2[k], w2[k * D + d], acc2);
  rel_f[(((size_t)l * R + r) * D + d) * 2 + b] = acc2;
}

// ---- merged pack kernel: rel (96 blocks) | lin_w (24) | mlp_w (8) ----
__global__ __launch_bounds__(256) void k_pack(
    const float2* __restrict__ rel2, unsigned int* __restrict__ rel_pk,
    const float* __restrict__ lin_w, unsigned short* __restrict__ Wf,
    const float* __restrict__ mlp_w, unsigned short* __restrict__ Wm) {
  int blk = blockIdx.x;
  int tid = threadIdx.x;
  if (blk < 96) {                    // rel: L*R*D = 24576 dwords
    int i = blk * 256 + tid;
    float2 v = rel2[i];
    rel_pk[i] = pack_h2(v.x, v.y);
  } else if (blk < 120) {            // lin_w: L*16 = 96 frag-groups, 4/block
    int idx = (blk - 96) * 4 + (tid >> 6);
    int lane = tid & 63;
    int l = idx >> 4, ct = (idx >> 2) & 3, ks = idx & 3;
    int n = ct * 16 + (lane & 15);
    #pragma unroll
    for (int j = 0; j < 8; ++j) {
      int k = ks * 32 + (lane >> 4) * 8 + j;
      _Float16 v = (_Float16)lin_w[(size_t)l * 2 * D * D + (size_t)k * D + n];
      Wf[(size_t)l * 8192 + ((size_t)((ct * 4 + ks) * 64) + lane) * 8 + j] =
          __builtin_bit_cast(unsigned short, v);
    }
  } else {                           // mlp_w: 32 frag-groups, 4/block
    int idx = (blk - 120) * 4 + (tid >> 6);
    int lane = tid & 63;
    int ct = idx >> 2, ks = idx & 3;
    int n = ct * 16 + (lane & 15);
    #pragma unroll
    for (int j = 0; j < 8; ++j) {
      int k = ks * 32 + (lane >> 4) * 8 + j;
      _Float16 v = (_Float16)mlp_w[(size_t)k * 2 * D + n];
      Wm[((size_t)idx * 64 + lane) * 8 + j] = __builtin_bit_cast(unsigned short, v);
    }
  }
}

// ---- CSR build ----
__global__ __launch_bounds__(256) void k_hist(const int* __restrict__ dst,
                                              int* __restrict__ cnt) {
  int e = blockIdx.x * 256 + threadIdx.x;
  if (e < E) atomicAdd(&cnt[dst[e]], 1);
}

__global__ __launch_bounds__(256) void k_scan1(const int* __restrict__ cnt,
                                               int* __restrict__ row_ptr,
                                               int* __restrict__ bsum) {
  __shared__ int s[256];
  int t = threadIdx.x;
  int i = blockIdx.x * 256 + t;
  int v = (i < N) ? cnt[i] : 0;
  s[t] = v;
  __syncthreads();
  #pragma unroll
  for (int off = 1; off < 256; off <<= 1) {   // Hillis-Steele inclusive
    int u = (t >= off) ? s[t - off] : 0;
    __syncthreads();
    s[t] += u;
    __syncthreads();
  }
  if (i < N) row_ptr[i] = s[t] - v;           // exclusive-in-block
  if (t == 255) bsum[blockIdx.x] = s[255];
}

// scan3: add prefix of block sums (block-reduced in LDS) + init cursor.
// row_ptr[N] = E (total is always E). Replaces the old scan2+scan3 pair.
__global__ __launch_bounds__(256) void k_scan3(int* __restrict__ row_ptr,
                                               const int* __restrict__ bsum,
                                               int* __restrict__ cursor) {
  __shared__ int red[256];
  int t = threadIdx.x;
  int v = (t < (int)blockIdx.x) ? bsum[t] : 0;   // blockIdx.x <= 156 < 256
  red[t] = v;
  __syncthreads();
  #pragma unroll
  for (int off = 128; off > 0; off >>= 1) {
    if (t < off) red[t] += red[t + off];
    __syncthreads();
  }
  int offv = red[0];
  int i = blockIdx.x * 256 + t;
  if (i < N) {
    int r = row_ptr[i] + offv;
    row_ptr[i] = r;
    cursor[i] = r;
  }
  if (i == N - 1) row_ptr[N] = E;
}

__global__ __launch_bounds__(256) void k_fill(const int* __restrict__ src,
                                              const int* __restrict__ dst,
                                              const int* __restrict__ etype,
                                              int* __restrict__ cursor,
                                              unsigned int* __restrict__ es) {
  int e = blockIdx.x * 256 + threadIdx.x;
  if (e < E) {
    int p = atomicAdd(&cursor[dst[e]], 1);
    es[p] = (unsigned int)src[e] | ((unsigned int)etype[e] << 16);  // src < 65536
  }
}

// ---- gather: TWO nodes per wave (half-wave each, uint2 8B loads/lane).
// Predicated unroll-8 main loop (16 loads in flight); deg<=32 fast path,
// overflow loop for deg>32 (P~0 at mean deg 10). Zero LDS.
// __launch_bounds__(256,6): ~85 VGPR cap, 24 waves/CU, no spills.
__global__ __launch_bounds__(256, 6) void k_gather(
    const unsigned int* __restrict__ xb,
    _Float16* __restrict__ xrow0, _Float16* __restrict__ xrow1,
    const unsigned int* __restrict__ rel_pk,     // [R*D] this layer, packed
    const int* __restrict__ row_ptr, const unsigned int* __restrict__ es,
    const float2* __restrict__ q2, const int* __restrict__ h_index, int first) {
  int tid = threadIdx.x;
  int lane = tid & 63;
  int h = lane >> 5;                 // half: 0 or 1
  int ln = lane & 31;                // lane within half (dims 2ln, 2ln+1)
  int w = (blockIdx.x * 256 + tid) >> 6;       // wave id in [0, N/2)
  int n = w * 2 + h;                 // node for this half
  int h0 = h_index[0], h1 = h_index[1];
  int rp = 0;
  if (lane < 3) rp = row_ptr[2 * w + lane];    // row_ptr[2w .. 2w+2]
  int rs = __shfl(rp, h);
  int re = __shfl(rp, h + 1);
  int deg = re - rs;
  int dc = min(deg, 32);
  unsigned int esv = 0;
  if (ln < dc) esv = es[rs + ln];              // half's edge list, one load
  float a0x = 0.f, a0y = 0.f, a1x = 0.f, a1y = 0.f;
  if (first) {
    // layer 0: x nonzero only at h0 (.x) / h1 (.y); loads only on match
    for (int j = 0; j < dc; ++j) {
      unsigned int pk = __shfl(esv, (h << 5) | j);
      int s = (int)(pk & 0xffffu), et = (int)(pk >> 16);
      if (s == h0 || s == h1) {
        uint2 xv = *(const uint2*)&xb[(size_t)s * D + 2 * ln];
        uint2 rv = *(const uint2*)&rel_pk[et * D + 2 * ln];
        float2 xfx = unpack_h2(xv.x), xfy = unpack_h2(xv.y);
        float2 rfx = unpack_h2(rv.x), rfy = unpack_h2(rv.y);
        if (s == h0) { a0x = fmaf(xfx.x, rfx.x, a0x); a0y = fmaf(xfy.x, rfy.x, a0y); }
        if (s == h1) { a1x = fmaf(xfx.y, rfx.y, a1x); a1y = fmaf(xfy.y, rfy.y, a1y); }
      }
    }
    for (int j = rs + 32; j < re; ++j) {       // overflow (rare)
      unsigned int pk = es[j];
      int s = (int)(pk & 0xffffu), et = (int)(pk >> 16);
      if (s == h0 || s == h1) {
        uint2 xv = *(const uint2*)&xb[(size_t)s * D + 2 * ln];
        uint2 rv = *(const uint2*)&rel_pk[et * D + 2 * ln];
        float2 xfx = unpack_h2(xv.x), xfy = unpack_h2(xv.y);
        float2 rfx = unpack_h2(rv.x), rfy = unpack_h2(rv.y);
        if (s == h0) { a0x = fmaf(xfx.x, rfx.x, a0x); a0y = fmaf(xfy.x, rfy.x, a0y); }
        if (s == h1) { a1x = fmaf(xfx.y, rfx.y, a1x); a1y = fmaf(xfy.y, rfy.y, a1y); }
      }
    }
  } else {
    int rounds = (dc + 7) >> 3;
    int maxr = max(__shfl(rounds, 0), __shfl(rounds, 32));   // wave-uniform bound
    for (int jr = 0; jr < maxr; ++jr) {
      int j = jr * 8;
      unsigned int pk[8];
      uint2 xv[8], rv[8];
      #pragma unroll
      for (int u = 0; u < 8; ++u) {
        int iu = max(min(j + u, dc - 1), 0);   // clamped (safe for done half)
        pk[u] = __shfl(esv, (h << 5) | iu);
      }
      #pragma unroll
      for (int u = 0; u < 8; ++u) {
        xv[u] = *(const uint2*)&xb[(size_t)(pk[u] & 0xffffu) * D + 2 * ln];
        rv[u] = *(const uint2*)&rel_pk[(pk[u] >> 16) * D + 2 * ln];
      }
      #pragma unroll
      for (int u = 0; u < 8; ++u) {
        if (j + u < dc) {
          float2 xfx = unpack_h2(xv[u].x), xfy = unpack_h2(xv[u].y);
          float2 rfx = unpack_h2(rv[u].x), rfy = unpack_h2(rv[u].y);
          a0x = fmaf(xfx.x, rfx.x, a0x); a1x = fmaf(xfx.y, rfx.y, a1x);
          a0y = fmaf(xfy.x, rfy.x, a0y); a1y = fmaf(xfy.y, rfy.y, a1y);
        }
      }
    }
    for (int j = rs + 32; j < re; ++j) {       // overflow (rare)
      unsigned int pk = es[j];
      uint2 xv = *(const uint2*)&xb[(size_t)(pk & 0xffffu) * D + 2 * ln];
      uint2 rv = *(const uint2*)&rel_pk[(pk >> 16) * D + 2 * ln];
      float2 xfx = unpack_h2(xv.x), xfy = unpack_h2(xv.y);
      float2 rfx = unpack_h2(rv.x), rfy = unpack_h2(rv.y);
      a0x = fmaf(xfx.x, rfx.x, a0x); a1x = fmaf(xfx.y, rfx.y, a1x);
      a0y = fmaf(xfy.x, rfy.x, a0y); a1y = fmaf(xfy.y, rfy.y, a1y);
    }
  }
  if (n == h0) {                     // + boundary (fp32)
    float4 qq = *(const float4*)&q2[2 * ln];
    a0x += qq.x; a0y += qq.z;
  }
  if (n == h1) {
    float4 qq = *(const float4*)&q2[2 * ln];
    a1x += qq.y; a1y += qq.w;
  }
  v2h s0; s0.x = (_Float16)a0x; s0.y = (_Float16)a0y;
  v2h s1; s1.x = (_Float16)a1x; s1.y = (_Float16)a1y;
  *(v2h*)&xrow0[(size_t)n * 2 * D + D + 2 * ln] = s0;   // agg-half of A rows
  *(v2h*)&xrow1[(size_t)n * 2 * D + D + 2 * ln] = s1;
}

// ---- MFMA linear + LN + relu + shortcut ----
// One wave per 16-node tile, both batches. Zero LDS. Grid 2500 x 64.
// Residual read from xb (f16) — no fp32 x buffer.
__global__ __launch_bounds__(64) void k_linear(
    unsigned int* __restrict__ xb,
    _Float16* __restrict__ xrow0, _Float16* __restrict__ xrow1,
    const unsigned short* __restrict__ Wf,
    const float* __restrict__ lin_b, const float* __restrict__ ln_g,
    const float* __restrict__ ln_b, int layer) {
  int lane = threadIdx.x;
  int nb = blockIdx.x * 16;
  int c = lane & 15, rg = lane >> 4;
  // B-fragments (16 x 16 B, L2-hot)
  const v8h* wf = (const v8h*)(Wf + (size_t)layer * 8192);
  v8h Bf[4][4];
  #pragma unroll
  for (int ct = 0; ct < 4; ++ct)
    #pragma unroll
    for (int ks = 0; ks < 4; ++ks)
      Bf[ct][ks] = wf[(ct * 4 + ks) * 64 + lane];
  v4f acc0[4], acc1[4];
  #pragma unroll
  for (int ct = 0; ct < 4; ++ct) {
    acc0[ct] = (v4f){0.f, 0.f, 0.f, 0.f};
    acc1[ct] = (v4f){0.f, 0.f, 0.f, 0.f};
  }
  // K-loop: 4 k-steps x (2 A-loads + 8 MFMA)
  #pragma unroll
  for (int ks = 0; ks < 4; ++ks) {
    size_t aoff = (size_t)(nb + c) * 2 * D + ks * 32 + rg * 8;
    v8h A0 = *(const v8h*)(xrow0 + aoff);
    v8h A1 = *(const v8h*)(xrow1 + aoff);
    #pragma unroll
    for (int ct = 0; ct < 4; ++ct) {
      acc0[ct] = __builtin_amdgcn_mfma_f32_16x16x32_f16(A0, Bf[ct][ks], acc0[ct], 0, 0, 0);
      acc1[ct] = __builtin_amdgcn_mfma_f32_16x16x32_f16(A1, Bf[ct][ks], acc1[ct], 0, 0, 0);
    }
  }
  // epilogue: +bias, LN over 64 outs (16-lane col-group x 4 ct), relu, +x
  float bias4[4], g4[4], be4[4];
  #pragma unroll
  for (int ct = 0; ct < 4; ++ct) {
    int d = ct * 16 + c;
    bias4[ct] = lin_b[layer * D + d];
    g4[ct]    = ln_g[layer * D + d];
    be4[ct]   = ln_b[layer * D + d];
  }
  #pragma unroll
  for (int j = 0; j < 4; ++j) {
    int node = nb + rg * 4 + j;
    float v0[4], v1[4];
    float s10 = 0.f, s20 = 0.f, s11 = 0.f, s21 = 0.f;
    #pragma unroll
    for (int ct = 0; ct < 4; ++ct) {
      v0[ct] = acc0[ct][j] + bias4[ct];
      v1[ct] = acc1[ct][j] + bias4[ct];
      s10 += v0[ct]; s20 += v0[ct] * v0[ct];
      s11 += v1[ct]; s21 += v1[ct] * v1[ct];
    }
    #pragma unroll
    for (int mk = 1; mk < 16; mk <<= 1) {   // reduce over the 16-lane col group
      s10 += __shfl_xor(s10, mk); s20 += __shfl_xor(s20, mk);
      s11 += __shfl_xor(s11, mk); s21 += __shfl_xor(s21, mk);
    }
    float mu0 = s10 * (1.f / D), var0 = s20 * (1.f / D) - mu0 * mu0;
    float mu1 = s11 * (1.f / D), var1 = s21 * (1.f / D) - mu1 * mu1;
    float rs0 = rsqrtf(var0 + EPS), rs1 = rsqrtf(var1 + EPS);
    #pragma unroll
    for (int ct = 0; ct < 4; ++ct) {
      int d = ct * 16 + c;
      float o0 = fmaxf((v0[ct] - mu0) * rs0 * g4[ct] + be4[ct], 0.f);
      float o1 = fmaxf((v1[ct] - mu1) * rs1 * g4[ct] + be4[ct], 0.f);
      float2 xv = unpack_h2(xb[(size_t)node * D + d]);    // f16 residual
      float r0 = o0 + xv.x, r1 = o1 + xv.y;
      xb[(size_t)node * D + d] = pack_h2(r0, r1);          // for gather / residual
      xrow0[(size_t)node * 2 * D + d] = (_Float16)r0;      // x-half for next linear/mlp
      xrow1[(size_t)node * 2 * D + d] = (_Float16)r1;
    }
  }
}

// ---- MFMA final MLP: relu([x, query] @ mlp_w + mlp_b) -> fp32 out ----
__global__ __launch_bounds__(64) void k_mlp(
    const _Float16* __restrict__ xrow0, const _Float16* __restrict__ xrow1,
    const _Float16* __restrict__ qh,            // [2][64] f16
    const unsigned short* __restrict__ Wm,      // 32 fragments
    const float* __restrict__ mlp_b,
    float* __restrict__ outf) {
  int lane = threadIdx.x;
  int nb = blockIdx.x * 16;
  int c = lane & 15, rg = lane >> 4;
  const v8h* wm = (const v8h*)Wm;
  v4f acc0[8], acc1[8];
  #pragma unroll
  for (int ct = 0; ct < 8; ++ct) {
    acc0[ct] = (v4f){0.f, 0.f, 0.f, 0.f};
    acc1[ct] = (v4f){0.f, 0.f, 0.f, 0.f};
  }
  #pragma unroll
  for (int ks = 0; ks < 4; ++ks) {
    v8h A0, A1;
    if (ks < 2) {                       // x half: k = ks*32 + rg*8 + j in [0,64)
      size_t aoff = (size_t)(nb + c) * 2 * D + ks * 32 + rg * 8;
      A0 = *(const v8h*)(xrow0 + aoff);
      A1 = *(const v8h*)(xrow1 + aoff);
    } else {                            // query half: node-invariant
      int qoff = (ks - 2) * 32 + rg * 8;
      A0 = *(const v8h*)(qh + qoff);
      A1 = *(const v8h*)(qh + D + qoff);
    }
    #pragma unroll
    for (int ct = 0; ct < 8; ++ct) {
      v8h Bv = wm[(ct * 4 + ks) * 64 + lane];
      acc0[ct] = __builtin_amdgcn_mfma_f32_16x16x32_f16(A0, Bv, acc0[ct], 0, 0, 0);
      acc1[ct] = __builtin_amdgcn_mfma_f32_16x16x32_f16(A1, Bv, acc1[ct], 0, 0, 0);
    }
  }
  // epilogue: +bias, relu, store. out flat = [2][N][128] fp32.
  #pragma unroll
  for (int ct = 0; ct < 8; ++ct) {
    int d = ct * 16 + c;
    float bias = mlp_b[d];
    #pragma unroll
    for (int j = 0; j < 4; ++j) {
      int node = nb + rg * 4 + j;
      outf[(size_t)node * 2 * D + d]       = fmaxf(acc0[ct][j] + bias, 0.f);
      outf[((size_t)N + node) * 2 * D + d] = fmaxf(acc1[ct][j] + bias, 0.f);
    }
  }
}

}  // namespace

extern "C" void kernel_launch(void* const* d_in, const int* in_sizes, int n_in,
                              void* d_out, int out_size, void* d_ws, size_t ws_size,
                              hipStream_t stream) {
  const float* rel_reps = (const float*)d_in[0];
  const int* h_index    = (const int*)d_in[1];
  const int* r_index    = (const int*)d_in[2];
  const int* edge_index = (const int*)d_in[3];
  const int* edge_type  = (const int*)d_in[4];
  const float* proj_w1  = (const float*)d_in[5];
  const float* proj_b1  = (const float*)d_in[6];
  const float* proj_w2  = (const float*)d_in[7];
  const float* proj_b2  = (const float*)d_in[8];
  const float* lin_w    = (const float*)d_in[9];
  const float* lin_b    = (const float*)d_in[10];
  const float* ln_g     = (const float*)d_in[11];
  const float* ln_b     = (const float*)d_in[12];
  const float* mlp_w    = (const float*)d_in[13];
  const float* mlp_b    = (const float*)d_in[14];

  // workspace: xb | xrow0 | xrow1 (one contiguous zero region, 30.7 MB) |
  //            rel_pk | Wf | Wm | qh | rel_all | query | cnt | row_ptr |
  //            cursor | es | bsum    (big 16B-aligned arrays first)
  unsigned int* xb = (unsigned int*)d_ws;                  // N*D
  _Float16* xrow0 = (_Float16*)(xb + (size_t)N * D);       // N*128
  _Float16* xrow1 = xrow0 + (size_t)N * 2 * D;             // N*128
  unsigned int* rel_pk = (unsigned int*)(xrow1 + (size_t)N * 2 * D);  // L*R*D
  unsigned short* Wf = (unsigned short*)(rel_pk + (size_t)L * R * D); // L*8192
  unsigned short* Wm = Wf + (size_t)L * 8192;              // 16384
  _Float16* qh = (_Float16*)(Wm + 16384);                  // 128
  float* rel_all = (float*)(qh + 128);                     // 2*L*R*D
  float* query   = rel_all + (size_t)2 * L * R * D;        // 2*D
  int*   cnt     = (int*)(query + 2 * D);
  int*   row_ptr = cnt + N;
  int*   cursor  = row_ptr + (N + 1);
  unsigned int* es = (unsigned int*)(cursor + N);
  int*   bsum    = (int*)(es + E);

  const int* srcp = edge_index;
  const int* dstp = edge_index + E;

  // one memset covers xb + xrow0 + xrow1 (contiguous)
  hipMemsetAsync(xb, 0, (size_t)N * D * 4 + (size_t)N * 2 * D * 2 * 2, stream);
  hipMemsetAsync(cnt, 0, N * sizeof(int), stream);
  k_rel<<<L * B * R + 1, 64, 0, stream>>>(rel_reps, proj_w1, proj_b1, proj_w2, proj_b2,
                                          rel_all, h_index, r_index,
                                          xb, xrow0, xrow1, query, qh);
  k_pack<<<128, 256, 0, stream>>>((const float2*)rel_all, rel_pk, lin_w, Wf, mlp_w, Wm);
  k_hist<<<EB, 256, 0, stream>>>(dstp, cnt);
  k_scan1<<<NB, 256, 0, stream>>>(cnt, row_ptr, bsum);
  k_scan3<<<NB, 256, 0, stream>>>(row_ptr, bsum, cursor);
  k_fill<<<EB, 256, 0, stream>>>(srcp, dstp, edge_type, cursor, es);

  for (int l = 0; l < L; ++l) {
    k_gather<<<N / 8, 256, 0, stream>>>(xb, xrow0, xrow1,
                                        rel_pk + (size_t)l * R * D,
                                        row_ptr, es, (const float2*)query, h_index,
                                        (l == 0) ? 1 : 0);
    k_linear<<<N / 16, 64, 0, stream>>>(xb, xrow0, xrow1,
                                        Wf, lin_b, ln_g, ln_b, l);
  }
  k_mlp<<<N / 16, 64, 0, stream>>>(xrow0, xrow1, qh, Wm, mlp_b, (float*)d_out);
}